// Round 3
// baseline (9092.543 us; speedup 1.0000x reference)
//
#include <hip/hip_runtime.h>

// ---------------------------------------------------------------------------
// Problem constants (B=4, T=4096, D=1024, H=8, DK=1024, DV=2048, RANK=16,
// LOOPD=128, n_loops=4)
// ---------------------------------------------------------------------------
#define BB 4
#define TT 4096
#define DD 1024
#define HH 8
#define DKK 1024
#define DVV 2048
#define MR (BB*TT)          // 16384 rows
#define DKH 128
#define DVH 256
#define NLOOPS 4

// Total workspace need (bytes): see layout in kernel_launch = 460,460,032
#define WS_NEED 460460032ull

// Static fallback workspace: allocated at module load (zero-init .bss-style),
// sidesteps any ws_size limitation. 460 MiB on a 288 GB card.
__device__ __attribute__((aligned(256))) unsigned char g_ws[WS_NEED];

typedef __bf16 bf16x8 __attribute__((ext_vector_type(8)));
typedef float  f32x4  __attribute__((ext_vector_type(4)));

__device__ __forceinline__ unsigned short f2bfu(float f) {
    unsigned int u = __builtin_bit_cast(unsigned int, f);
    u += 0x7fffu + ((u >> 16) & 1u);
    return (unsigned short)(u >> 16);
}
__device__ __forceinline__ float bfu2f(unsigned short s) {
    unsigned int u = ((unsigned int)s) << 16;
    return __builtin_bit_cast(float, u);
}
__device__ __forceinline__ float blo(int u) {
    return __builtin_bit_cast(float, ((unsigned int)u) << 16);
}
__device__ __forceinline__ float bhi(int u) {
    return __builtin_bit_cast(float, ((unsigned int)u) & 0xffff0000u);
}

__device__ __forceinline__ void gld_lds16(const void* g, void* l) {
    __builtin_amdgcn_global_load_lds(
        (__attribute__((address_space(1))) void*)const_cast<void*>(g),
        (__attribute__((address_space(3))) void*)l, 16, 0, 0);
}

// ---------------------------------------------------------------------------
// Weight prep: fp32 [K][N] -> bf16 [N][K]  (B^T layout for the MFMA GEMM)
// ---------------------------------------------------------------------------
__global__ __launch_bounds__(256) void k_transpose_bf16(
    const float* __restrict__ in, unsigned short* __restrict__ out, int K, int N)
{
    __shared__ float tile[64][65];
    int k0 = blockIdx.y * 64, n0 = blockIdx.x * 64;
    int tx = threadIdx.x & 63, ty = threadIdx.x >> 6;
    #pragma unroll
    for (int r = 0; r < 64; r += 4)
        tile[ty + r][tx] = in[(size_t)(k0 + ty + r) * N + n0 + tx];
    __syncthreads();
    #pragma unroll
    for (int r = 0; r < 64; r += 4)
        out[(size_t)(n0 + ty + r) * K + k0 + tx] = f2bfu(tile[tx][ty + r]);
}

// plain fp32 -> bf16 convert (grid*256*4 == n)
__global__ __launch_bounds__(256) void k_convert_bf16(
    const float* __restrict__ in, unsigned short* __restrict__ out)
{
    size_t i = ((size_t)blockIdx.x * 256 + threadIdx.x) * 4;
    float4 v = *(const float4*)&in[i];
    ushort4 o = make_ushort4(f2bfu(v.x), f2bfu(v.y), f2bfu(v.z), f2bfu(v.w));
    *(ushort4*)&out[i] = o;
}

// inj_A: bf16 convert with diagonal zeroed; diagonal extracted to fp32 vector
__global__ __launch_bounds__(256) void k_conv_injA(
    const float* __restrict__ in, unsigned short* __restrict__ out,
    float* __restrict__ diag)
{
    int idx = blockIdx.x * 256 + threadIdx.x;      // over 1024*1024
    int i = idx >> 10, j = idx & 1023;
    float v = in[idx];
    if (i == j) { diag[i] = v; out[idx] = 0; }
    else        { out[idx] = f2bfu(v); }
}

// ---------------------------------------------------------------------------
// prep: h[:, :128] += loop_table[t]; xn = rmsnorm(h+e)*w -> bf16; h -> bf16
// grid = MR blocks of 256
// ---------------------------------------------------------------------------
__global__ __launch_bounds__(256) void k_prep(
    float* __restrict__ h, const float* __restrict__ e,
    const float* __restrict__ norm_w, const float* __restrict__ ltab,
    unsigned short* __restrict__ h_bf, unsigned short* __restrict__ xn_bf)
{
    int row = blockIdx.x, tid = threadIdx.x;
    size_t base = (size_t)row * DD + tid * 4;
    float4 hv = *(float4*)&h[base];
    if (tid < 32) {
        float4 lv = *(const float4*)&ltab[tid * 4];
        hv.x += lv.x; hv.y += lv.y; hv.z += lv.z; hv.w += lv.w;
        *(float4*)&h[base] = hv;
    }
    float4 ev = *(const float4*)&e[base];
    float sx = hv.x + ev.x, sy = hv.y + ev.y, sz = hv.z + ev.z, sw = hv.w + ev.w;
    float partial = sx*sx + sy*sy + sz*sz + sw*sw;
    __shared__ float red[256];
    red[tid] = partial; __syncthreads();
    for (int st = 128; st > 0; st >>= 1) {
        if (tid < st) red[tid] += red[tid + st];
        __syncthreads();
    }
    float rms = rsqrtf(red[0] * (1.0f / DD) + 1e-6f);
    float4 wv = *(const float4*)&norm_w[tid * 4];
    *(ushort4*)&xn_bf[base] = make_ushort4(
        f2bfu(sx * rms * wv.x), f2bfu(sy * rms * wv.y),
        f2bfu(sz * rms * wv.z), f2bfu(sw * rms * wv.w));
    *(ushort4*)&h_bf[base] = make_ushort4(f2bfu(hv.x), f2bfu(hv.y), f2bfu(hv.z), f2bfu(hv.w));
}

// ---------------------------------------------------------------------------
// MFMA GEMM: C[M,N] = A[M,K](bf16) @ Bt[N,K](bf16)^T  (+ epilogue)
// EPI: 0=none 1=*escale 2=exp(logsigmoid(x)/16)
// OUTBF: 1 -> bf16 out, 0 -> fp32 out
// HASADD: += addend[oi] (fp32)      HASDIAG: += hsrc[oi]*diag[gn] (fp32)
// block 256 (4 waves, 2x2), tile 128x128, BK=32
// ---------------------------------------------------------------------------
template<int EPI, int OUTBF, int HASADD, int HASDIAG>
__global__ __launch_bounds__(256) void k_gemm(
    const unsigned short* __restrict__ A, const unsigned short* __restrict__ Bt,
    void* __restrict__ outp, const float* __restrict__ addend,
    const float* __restrict__ hsrc, const float* __restrict__ diag,
    int N, int K, float escale)
{
    __shared__ unsigned short lsA[128 * 32];
    __shared__ unsigned short lsB[128 * 32];
    int tid = threadIdx.x, lane = tid & 63, wave = tid >> 6;
    int wm = wave >> 1, wn = wave & 1;
    int bm = blockIdx.y * 128, bn = blockIdx.x * 128;
    int lrow = lane >> 2, lcol = (lane & 3) * 8;

    f32x4 acc[4][4];
    #pragma unroll
    for (int i = 0; i < 4; ++i)
        #pragma unroll
        for (int j = 0; j < 4; ++j) {
            f32x4 z = {0.f, 0.f, 0.f, 0.f};
            acc[i][j] = z;
        }

    for (int k0 = 0; k0 < K; k0 += 32) {
        __syncthreads();
        #pragma unroll
        for (int r = 0; r < 2; ++r) {
            int row = r * 64 + wave * 16 + lrow;
            gld_lds16(A  + (size_t)(bm + row) * K + k0 + lcol, &lsA[row * 32 + lcol]);
            gld_lds16(Bt + (size_t)(bn + row) * K + k0 + lcol, &lsB[row * 32 + lcol]);
        }
        __syncthreads();
        int quad = lane >> 4, mr = lane & 15;
        bf16x8 av[4], bv[4];
        #pragma unroll
        for (int t2 = 0; t2 < 4; ++t2) {
            av[t2] = *(const bf16x8*)&lsA[(wm * 64 + t2 * 16 + mr) * 32 + quad * 8];
            bv[t2] = *(const bf16x8*)&lsB[(wn * 64 + t2 * 16 + mr) * 32 + quad * 8];
        }
        #pragma unroll
        for (int tm = 0; tm < 4; ++tm)
            #pragma unroll
            for (int tn = 0; tn < 4; ++tn)
                acc[tm][tn] = __builtin_amdgcn_mfma_f32_16x16x32_bf16(
                    av[tm], bv[tn], acc[tm][tn], 0, 0, 0);
    }

    int quad = lane >> 4, col = lane & 15;
    float* outf = (float*)outp;
    unsigned short* outb = (unsigned short*)outp;
    #pragma unroll
    for (int tm = 0; tm < 4; ++tm) {
        int gm0 = bm + wm * 64 + tm * 16 + quad * 4;
        #pragma unroll
        for (int tn = 0; tn < 4; ++tn) {
            int gn = bn + wn * 64 + tn * 16 + col;
            #pragma unroll
            for (int r = 0; r < 4; ++r) {
                float val = acc[tm][tn][r];
                if (EPI == 1) val *= escale;
                if (EPI == 2) {
                    float ls = fminf(val, 0.f) - log1pf(expf(-fabsf(val)));
                    val = expf(ls * 0.0625f);
                }
                size_t oi = (size_t)(gm0 + r) * N + gn;
                if (HASDIAG) val += hsrc[oi] * diag[gn];
                if (HASADD)  val += addend[oi];
                if (OUTBF) outb[oi] = f2bfu(val);
                else       outf[oi] = val;
            }
        }
    }
}

// ---------------------------------------------------------------------------
// GLA scan.  grid = (16 colgroups, 1, B*H), block 256.
// Thread (jloc=tid>>4, isub=tid&15) owns 8 state rows (i = isub*8..isub*8+7)
// of column j0+jloc.  S[i][j] = a[i]*S + k[i]*v[j];  o[j] = sum_i q[i]*S[i][j]
// (16-lane shfl reduce).  Single bf16 output buffer.
// ---------------------------------------------------------------------------
__global__ __launch_bounds__(256) void k_scan(
    const unsigned short* __restrict__ q, const unsigned short* __restrict__ kk,
    const unsigned short* __restrict__ v, const float* __restrict__ al,
    unsigned short* __restrict__ ob)
{
    int bh = blockIdx.z; int b = bh >> 3, h = bh & 7;
    int j0 = blockIdx.x * 16;
    int tid = threadIdx.x, jloc = tid >> 4, isub = tid & 15;

    __shared__ unsigned short lq[32 * 128], lk[32 * 128], lv[32 * 16];
    __shared__ float la[32 * 128];

    float S[8];
    #pragma unroll
    for (int r = 0; r < 8; ++r) S[r] = 0.f;

    size_t rowbase = (size_t)b * TT;
    for (int c0 = 0; c0 < TT; c0 += 32) {
        __syncthreads();
        #pragma unroll
        for (int it = 0; it < 2; ++it) {   // q,k: 32 steps x 128 i (bf16)
            int idx = it * 256 + tid;
            int s = idx >> 4, i8 = (idx & 15) * 8;
            size_t g = (rowbase + c0 + s) * DKK + h * DKH + i8;
            *(int4*)&lq[s * 128 + i8] = *(const int4*)&q[g];
            *(int4*)&lk[s * 128 + i8] = *(const int4*)&kk[g];
        }
        #pragma unroll
        for (int it = 0; it < 4; ++it) {   // alpha: 32 x 128 fp32
            int idx = it * 256 + tid;
            int s = idx >> 5, i4 = (idx & 31) * 4;
            size_t g = (rowbase + c0 + s) * DKK + h * DKH + i4;
            *(float4*)&la[s * 128 + i4] = *(const float4*)&al[g];
        }
        if (tid < 64) {                    // v: 32 steps x 16 cols
            int s = tid >> 1, jj8 = (tid & 1) * 8;
            size_t g = (rowbase + c0 + s) * DVV + h * DVH + j0 + jj8;
            *(int4*)&lv[s * 16 + jj8] = *(const int4*)&v[g];
        }
        __syncthreads();

        for (int s = 0; s < 32; ++s) {
            float vj = bfu2f(lv[s * 16 + jloc]);
            float4 aA = *(const float4*)&la[s * 128 + isub * 8];
            float4 aB = *(const float4*)&la[s * 128 + isub * 8 + 4];
            int4 kr = *(const int4*)&lk[s * 128 + isub * 8];
            int4 qr = *(const int4*)&lq[s * 128 + isub * 8];
            float av8[8] = {aA.x, aA.y, aA.z, aA.w, aB.x, aB.y, aB.z, aB.w};
            int kw[4] = {kr.x, kr.y, kr.z, kr.w};
            int qw[4] = {qr.x, qr.y, qr.z, qr.w};
            float qa = 0.f;
            #pragma unroll
            for (int r = 0; r < 4; ++r) {
                float kl = blo(kw[r]), kh2 = bhi(kw[r]);
                float ql = blo(qw[r]), qh2 = bhi(qw[r]);
                S[2*r]   = fmaf(av8[2*r],   S[2*r],   kl  * vj);
                qa = fmaf(ql,  S[2*r],   qa);
                S[2*r+1] = fmaf(av8[2*r+1], S[2*r+1], kh2 * vj);
                qa = fmaf(qh2, S[2*r+1], qa);
            }
            qa += __shfl_xor(qa, 1);
            qa += __shfl_xor(qa, 2);
            qa += __shfl_xor(qa, 4);
            qa += __shfl_xor(qa, 8);
            if (isub == 0)
                ob[(rowbase + c0 + s) * DVV + h * DVH + j0 + jloc] = f2bfu(qa);
        }
    }
}

// ---------------------------------------------------------------------------
// gate: o <- bf16( o * silu(xg) )   elementwise over MR*DVV
// ---------------------------------------------------------------------------
__global__ __launch_bounds__(256) void k_gate(
    unsigned short* __restrict__ o0, const unsigned short* __restrict__ xg)
{
    size_t i = ((size_t)blockIdx.x * 256 + threadIdx.x) * 8;
    union { int4 v; unsigned short u[8]; } A, G, R;
    A.v = *(const int4*)&o0[i];
    G.v = *(const int4*)&xg[i];
    #pragma unroll
    for (int j = 0; j < 8; ++j) {
        float ov = bfu2f(A.u[j]);
        float xf = bfu2f(G.u[j]);
        float sg = xf / (1.f + expf(-xf));
        R.u[j] = f2bfu(ov * sg);
    }
    *(int4*)&o0[i] = R.v;
}

// ---------------------------------------------------------------------------
// LoRA rank-16, fp32.  lora1: tmp[row,16] = G[row,:] @ A[1024,16]
// one wave per row, grid = MR/4
// ---------------------------------------------------------------------------
__global__ __launch_bounds__(256) void k_lora1(
    const float* __restrict__ G, const float* __restrict__ A, float* __restrict__ tmp)
{
    int row = blockIdx.x * 4 + (threadIdx.x >> 6);
    int lane = threadIdx.x & 63;
    float acc[16];
    #pragma unroll
    for (int r = 0; r < 16; ++r) acc[r] = 0.f;
    const float* grow = G + (size_t)row * DD;
    for (int k2 = lane; k2 < DD; k2 += 64) {
        float g = grow[k2];
        const float4* ar = (const float4*)(A + k2 * 16);
        float4 a0 = ar[0], a1 = ar[1], a2 = ar[2], a3 = ar[3];
        acc[0] = fmaf(g, a0.x, acc[0]);  acc[1] = fmaf(g, a0.y, acc[1]);
        acc[2] = fmaf(g, a0.z, acc[2]);  acc[3] = fmaf(g, a0.w, acc[3]);
        acc[4] = fmaf(g, a1.x, acc[4]);  acc[5] = fmaf(g, a1.y, acc[5]);
        acc[6] = fmaf(g, a1.z, acc[6]);  acc[7] = fmaf(g, a1.w, acc[7]);
        acc[8] = fmaf(g, a2.x, acc[8]);  acc[9] = fmaf(g, a2.y, acc[9]);
        acc[10] = fmaf(g, a2.z, acc[10]); acc[11] = fmaf(g, a2.w, acc[11]);
        acc[12] = fmaf(g, a3.x, acc[12]); acc[13] = fmaf(g, a3.y, acc[13]);
        acc[14] = fmaf(g, a3.z, acc[14]); acc[15] = fmaf(g, a3.w, acc[15]);
    }
    #pragma unroll
    for (int off = 32; off >= 1; off >>= 1)
        #pragma unroll
        for (int r = 0; r < 16; ++r) acc[r] += __shfl_xor(acc[r], off);
    if (lane == 0) {
        #pragma unroll
        for (int r = 0; r < 16; ++r) tmp[(size_t)row * 16 + r] = acc[r];
    }
}

// lora2: G[row,:] += tmp[row,:] @ Bm[16,1024]     grid = MR
__global__ __launch_bounds__(256) void k_lora2(
    float* __restrict__ G, const float* __restrict__ tmp, const float* __restrict__ Bm)
{
    int row = blockIdx.x, tid = threadIdx.x;
    __shared__ float t16[16];
    if (tid < 16) t16[tid] = tmp[(size_t)row * 16 + tid];
    __syncthreads();
    size_t base = (size_t)row * DD + tid * 4;
    float4 acc = *(float4*)&G[base];
    #pragma unroll
    for (int r = 0; r < 16; ++r) {
        float tv = t16[r];
        float4 bv = *(const float4*)&Bm[r * DD + tid * 4];
        acc.x = fmaf(tv, bv.x, acc.x); acc.y = fmaf(tv, bv.y, acc.y);
        acc.z = fmaf(tv, bv.z, acc.z); acc.w = fmaf(tv, bv.w, acc.w);
    }
    *(float4*)&G[base] = acc;
}

// ---------------------------------------------------------------------------
// ACT halting.  grid = MR.  cum/halted staged through LDS (race-free).
// Accumulates weighted h into out (d_out).
// ---------------------------------------------------------------------------
__global__ __launch_bounds__(256) void k_act(
    const float* __restrict__ h, const float* __restrict__ act_w,
    const float* __restrict__ act_b, float* __restrict__ out,
    float* __restrict__ cum, int* __restrict__ halted)
{
    int row = blockIdx.x, tid = threadIdx.x;
    size_t base = (size_t)row * DD + tid * 4;
    float4 hv = *(const float4*)&h[base];
    float4 wv = *(const float4*)&act_w[tid * 4];
    float partial = hv.x*wv.x + hv.y*wv.y + hv.z*wv.z + hv.w*wv.w;
    __shared__ float red[256];
    __shared__ float s_cm;
    __shared__ int s_hl;
    if (tid == 0) { s_cm = cum[row]; s_hl = halted[row]; }
    red[tid] = partial; __syncthreads();
    for (int st = 128; st > 0; st >>= 1) {
        if (tid < st) red[tid] += red[tid + st];
        __syncthreads();
    }
    float p = 1.f / (1.f + expf(-(red[0] + act_b[0])));
    float cm = s_cm;
    int hl = s_hl;
    float p_eff = hl ? 0.f : p;
    float ncum = cm + p_eff;
    int newly = (!hl) && (ncum >= 0.99f);
    float w = newly ? (1.f - cm) : p_eff;
    float4 ho = *(float4*)&out[base];
    ho.x += w * hv.x; ho.y += w * hv.y; ho.z += w * hv.z; ho.w += w * hv.w;
    *(float4*)&out[base] = ho;
    if (tid == 0) { cum[row] = ncum; halted[row] = hl | newly; }
}

// final: io = rmsnorm(io) * out_norm_w  (in place on d_out)    grid = MR
__global__ __launch_bounds__(256) void k_final(
    float* __restrict__ io, const float* __restrict__ w)
{
    int row = blockIdx.x, tid = threadIdx.x;
    size_t base = (size_t)row * DD + tid * 4;
    float4 hv = *(const float4*)&io[base];
    float partial = hv.x*hv.x + hv.y*hv.y + hv.z*hv.z + hv.w*hv.w;
    __shared__ float red[256];
    red[tid] = partial; __syncthreads();
    for (int st = 128; st > 0; st >>= 1) {
        if (tid < st) red[tid] += red[tid + st];
        __syncthreads();
    }
    float rms = rsqrtf(red[0] * (1.0f / DD) + 1e-6f);
    float4 wv = *(const float4*)&w[tid * 4];
    float4 o = make_float4(hv.x*rms*wv.x, hv.y*rms*wv.y, hv.z*rms*wv.z, hv.w*rms*wv.w);
    *(float4*)&io[base] = o;
}

// ---------------------------------------------------------------------------
extern "C" void kernel_launch(void* const* d_in, const int* in_sizes, int n_in,
                              void* d_out, int out_size, void* d_ws, size_t ws_size,
                              hipStream_t stream)
{
    const float* in_h       = (const float*)d_in[0];
    const float* in_e       = (const float*)d_in[1];
    const float* norm_w     = (const float*)d_in[2];
    const float* out_norm_w = (const float*)d_in[3];
    const float* Wq   = (const float*)d_in[4];
    const float* Wk   = (const float*)d_in[5];
    const float* Wv   = (const float*)d_in[6];
    const float* Wgk  = (const float*)d_in[7];
    const float* Wg   = (const float*)d_in[8];
    const float* Wo   = (const float*)d_in[9];
    const float* lora_A = (const float*)d_in[10];
    const float* lora_B = (const float*)d_in[11];
    const float* inj_A  = (const float*)d_in[12];
    const float* inj_B  = (const float*)d_in[13];
    const float* act_w  = (const float*)d_in[14];
    const float* act_b  = (const float*)d_in[15];
    const float* loop_table = (const float*)d_in[16];

    // Pick workspace: harness d_ws if big enough, else the 460 MiB static
    // device buffer (allocated at module load; graph-capture-safe lookup).
    char* p;
    if (ws_size >= WS_NEED) {
        p = (char*)d_ws;
    } else {
        void* sym = nullptr;
        hipGetSymbolAddress(&sym, HIP_SYMBOL(g_ws));
        p = (char*)sym;
    }

    float* h      = (float*)p;            p += (size_t)MR * DD * 4;     // 64 MiB
    unsigned short* h_bf  = (unsigned short*)p; p += (size_t)MR * DD * 2;   // 32
    unsigned short* e_bf  = (unsigned short*)p; p += (size_t)MR * DD * 2;   // 32
    unsigned short* xn_bf = (unsigned short*)p; p += (size_t)MR * DD * 2;   // 32
    unsigned short* q_bf  = (unsigned short*)p; p += (size_t)MR * DKK * 2;  // 32
    unsigned short* k_bf  = (unsigned short*)p; p += (size_t)MR * DKK * 2;  // 32
    unsigned short* v_bf  = (unsigned short*)p; p += (size_t)MR * DVV * 2;  // 64
    float* alpha  = (float*)p;            p += (size_t)MR * DKK * 4;        // 64
    unsigned short* ob0   = (unsigned short*)p; p += (size_t)MR * DVV * 2;  // 64
    unsigned short* WqT  = (unsigned short*)p; p += (size_t)DKK * DD * 2;
    unsigned short* WkT  = (unsigned short*)p; p += (size_t)DKK * DD * 2;
    unsigned short* WgkT = (unsigned short*)p; p += (size_t)DKK * DD * 2;
    unsigned short* WvT  = (unsigned short*)p; p += (size_t)DVV * DD * 2;
    unsigned short* WgT  = (unsigned short*)p; p += (size_t)DVV * DD * 2;
    unsigned short* WoT  = (unsigned short*)p; p += (size_t)DD * DVV * 2;
    unsigned short* injA_bf = (unsigned short*)p; p += (size_t)DD * DD * 2;
    unsigned short* injB_bf = (unsigned short*)p; p += (size_t)DD * DD * 2;
    float* diagA = (float*)p;             p += DD * 4;
    float* tmp16 = (float*)p;             p += (size_t)MR * 16 * 4;
    float* cum   = (float*)p;             p += MR * 4;
    int*   halted = (int*)p;              p += MR * 4;
    // Aliases (lifetime-checked):
    unsigned short* xg_bf = q_bf;   // Wg GEMM runs AFTER scan; q,k dead then (64 MiB)
    float* g2 = alpha;              // alpha dead after scan
    float* t1 = (float*)ob0;        // ob0 dead after Wo GEMM
    float* h_out = (float*)d_out;   // accumulate ACT output directly in d_out

    // per-launch init
    hipMemcpyAsync(h, in_h, (size_t)MR * DD * 4, hipMemcpyDeviceToDevice, stream);
    hipMemsetAsync(h_out, 0, (size_t)MR * DD * 4, stream);
    hipMemsetAsync(cum, 0, MR * 4, stream);
    hipMemsetAsync(halted, 0, MR * 4, stream);

    // weight prep (every launch; small vs total work)
    k_transpose_bf16<<<dim3(16, 16), 256, 0, stream>>>(Wq,  WqT,  DD, DKK);
    k_transpose_bf16<<<dim3(16, 16), 256, 0, stream>>>(Wk,  WkT,  DD, DKK);
    k_transpose_bf16<<<dim3(16, 16), 256, 0, stream>>>(Wgk, WgkT, DD, DKK);
    k_transpose_bf16<<<dim3(32, 16), 256, 0, stream>>>(Wv,  WvT,  DD, DVV);
    k_transpose_bf16<<<dim3(32, 16), 256, 0, stream>>>(Wg,  WgT,  DD, DVV);
    k_transpose_bf16<<<dim3(16, 32), 256, 0, stream>>>(Wo,  WoT,  DVV, DD);
    k_conv_injA<<<4096, 256, 0, stream>>>(inj_A, injA_bf, diagA);
    k_convert_bf16<<<1024, 256, 0, stream>>>(inj_B, injB_bf);
    k_convert_bf16<<<MR * DD / 1024, 256, 0, stream>>>(in_e, e_bf);

    const float qscale = 0.08838834764831845f;   // 128^-0.5

    for (int t = 0; t < NLOOPS; ++t) {
        k_prep<<<MR, 256, 0, stream>>>(h, in_e, norm_w, loop_table + t * 128, h_bf, xn_bf);

        k_gemm<1,1,0,0><<<dim3(DKK/128, MR/128), 256, 0, stream>>>(
            xn_bf, WqT, q_bf, nullptr, nullptr, nullptr, DKK, DD, qscale);
        k_gemm<0,1,0,0><<<dim3(DKK/128, MR/128), 256, 0, stream>>>(
            xn_bf, WkT, k_bf, nullptr, nullptr, nullptr, DKK, DD, 1.f);
        k_gemm<2,0,0,0><<<dim3(DKK/128, MR/128), 256, 0, stream>>>(
            xn_bf, WgkT, alpha, nullptr, nullptr, nullptr, DKK, DD, 1.f);
        k_gemm<0,1,0,0><<<dim3(DVV/128, MR/128), 256, 0, stream>>>(
            xn_bf, WvT, v_bf, nullptr, nullptr, nullptr, DVV, DD, 1.f);

        k_scan<<<dim3(16, 1, BB * HH), 256, 0, stream>>>(q_bf, k_bf, v_bf, alpha, ob0);

        // Wg projection AFTER scan so xg can reuse q/k space
        k_gemm<0,1,0,0><<<dim3(DVV/128, MR/128), 256, 0, stream>>>(
            xn_bf, WgT, xg_bf, nullptr, nullptr, nullptr, DVV, DD, 1.f);

        k_gate<<<(int)((size_t)MR * DVV / 2048), 256, 0, stream>>>(ob0, xg_bf);

        k_gemm<0,0,0,0><<<dim3(DD/128, MR/128), 256, 0, stream>>>(
            ob0, WoT, g2, nullptr, nullptr, nullptr, DD, DVV, 1.f);

        k_lora1<<<MR / 4, 256, 0, stream>>>(g2, lora_A + (size_t)t * DD * 16, tmp16);
        k_lora2<<<MR, 256, 0, stream>>>(g2, tmp16, lora_B + (size_t)t * 16 * DD);

        // t1 = h @ inj_A^T (off-diag bf16 + fp32 diag) + g2
        k_gemm<0,0,1,1><<<dim3(DD/128, MR/128), 256, 0, stream>>>(
            h_bf, injA_bf, t1, g2, h, diagA, DD, DD, 1.f);
        // h = e @ inj_B^T + t1
        k_gemm<0,0,1,0><<<dim3(DD/128, MR/128), 256, 0, stream>>>(
            e_bf, injB_bf, h, t1, nullptr, nullptr, DD, DD, 1.f);

        k_act<<<MR, 256, 0, stream>>>(h, act_w, act_b, h_out, cum, halted);
    }

    k_final<<<MR, 256, 0, stream>>>(h_out, out_norm_w);
}

// Round 4
// 5047.055 us; speedup vs baseline: 1.8016x; 1.8016x over previous
//
#include <hip/hip_runtime.h>

// ---------------------------------------------------------------------------
// Problem constants (B=4, T=4096, D=1024, H=8, DK=1024, DV=2048, RANK=16,
// LOOPD=128, n_loops=4)
// ---------------------------------------------------------------------------
#define BB 4
#define TT 4096
#define DD 1024
#define HH 8
#define DKK 1024
#define DVV 2048
#define MR (BB*TT)          // 16384 rows
#define DKH 128
#define DVH 256
#define NLOOPS 4
#define LCH 128             // scan chunk length
#define NCH (TT/LCH)        // 32 chunks per batch
#define PADW 136            // LDS row stride (shorts): 128 + 8 pad (breaks bank aliasing, keeps 16B align)

// Total workspace need (bytes) for the layout in kernel_launch
#define WS_NEED 595202048ull

// Static fallback workspace (module-load allocated; used when ws_size < WS_NEED)
__device__ __attribute__((aligned(256))) unsigned char g_ws[WS_NEED];

typedef __bf16 bf16x8 __attribute__((ext_vector_type(8)));
typedef float  f32x4  __attribute__((ext_vector_type(4)));

__device__ __forceinline__ unsigned short f2bfu(float f) {
    unsigned int u = __builtin_bit_cast(unsigned int, f);
    u += 0x7fffu + ((u >> 16) & 1u);
    return (unsigned short)(u >> 16);
}
__device__ __forceinline__ float bfu2f(unsigned short s) {
    unsigned int u = ((unsigned int)s) << 16;
    return __builtin_bit_cast(float, u);
}

__device__ __forceinline__ void gld_lds16(const void* g, void* l) {
    __builtin_amdgcn_global_load_lds(
        (__attribute__((address_space(1))) void*)const_cast<void*>(g),
        (__attribute__((address_space(3))) void*)l, 16, 0, 0);
}

// ---------------------------------------------------------------------------
// Weight prep: fp32 [K][N] -> bf16 [N][K]  (B^T layout for the MFMA GEMM)
// ---------------------------------------------------------------------------
__global__ __launch_bounds__(256) void k_transpose_bf16(
    const float* __restrict__ in, unsigned short* __restrict__ out, int K, int N)
{
    __shared__ float tile[64][65];
    int k0 = blockIdx.y * 64, n0 = blockIdx.x * 64;
    int tx = threadIdx.x & 63, ty = threadIdx.x >> 6;
    #pragma unroll
    for (int r = 0; r < 64; r += 4)
        tile[ty + r][tx] = in[(size_t)(k0 + ty + r) * N + n0 + tx];
    __syncthreads();
    #pragma unroll
    for (int r = 0; r < 64; r += 4)
        out[(size_t)(n0 + ty + r) * K + k0 + tx] = f2bfu(tile[tx][ty + r]);
}

__global__ __launch_bounds__(256) void k_convert_bf16(
    const float* __restrict__ in, unsigned short* __restrict__ out)
{
    size_t i = ((size_t)blockIdx.x * 256 + threadIdx.x) * 4;
    float4 v = *(const float4*)&in[i];
    ushort4 o = make_ushort4(f2bfu(v.x), f2bfu(v.y), f2bfu(v.z), f2bfu(v.w));
    *(ushort4*)&out[i] = o;
}

__global__ __launch_bounds__(256) void k_conv_injA(
    const float* __restrict__ in, unsigned short* __restrict__ out,
    float* __restrict__ diag)
{
    int idx = blockIdx.x * 256 + threadIdx.x;      // over 1024*1024
    int i = idx >> 10, j = idx & 1023;
    float v = in[idx];
    if (i == j) { diag[i] = v; out[idx] = 0; }
    else        { out[idx] = f2bfu(v); }
}

// ---------------------------------------------------------------------------
// prep: h[:, :128] += loop_table[t]; xn = rmsnorm(h+e)*w -> bf16; h -> bf16
// ---------------------------------------------------------------------------
__global__ __launch_bounds__(256) void k_prep(
    float* __restrict__ h, const float* __restrict__ e,
    const float* __restrict__ norm_w, const float* __restrict__ ltab,
    unsigned short* __restrict__ h_bf, unsigned short* __restrict__ xn_bf)
{
    int row = blockIdx.x, tid = threadIdx.x;
    size_t base = (size_t)row * DD + tid * 4;
    float4 hv = *(float4*)&h[base];
    if (tid < 32) {
        float4 lv = *(const float4*)&ltab[tid * 4];
        hv.x += lv.x; hv.y += lv.y; hv.z += lv.z; hv.w += lv.w;
        *(float4*)&h[base] = hv;
    }
    float4 ev = *(const float4*)&e[base];
    float sx = hv.x + ev.x, sy = hv.y + ev.y, sz = hv.z + ev.z, sw = hv.w + ev.w;
    float partial = sx*sx + sy*sy + sz*sz + sw*sw;
    __shared__ float red[256];
    red[tid] = partial; __syncthreads();
    for (int st = 128; st > 0; st >>= 1) {
        if (tid < st) red[tid] += red[tid + st];
        __syncthreads();
    }
    float rms = rsqrtf(red[0] * (1.0f / DD) + 1e-6f);
    float4 wv = *(const float4*)&norm_w[tid * 4];
    *(ushort4*)&xn_bf[base] = make_ushort4(
        f2bfu(sx * rms * wv.x), f2bfu(sy * rms * wv.y),
        f2bfu(sz * rms * wv.z), f2bfu(sw * rms * wv.w));
    *(ushort4*)&h_bf[base] = make_ushort4(f2bfu(hv.x), f2bfu(hv.y), f2bfu(hv.z), f2bfu(hv.w));
}

// ---------------------------------------------------------------------------
// MFMA GEMM: C[M,N] = A[M,K](bf16) @ Bt[N,K](bf16)^T  (+ epilogue)
// EPI: 0=none 1=*escale 2=logsigmoid(x)/16 (fp32 log-decay out)
// ---------------------------------------------------------------------------
template<int EPI, int OUTBF, int HASADD, int HASDIAG>
__global__ __launch_bounds__(256) void k_gemm(
    const unsigned short* __restrict__ A, const unsigned short* __restrict__ Bt,
    void* __restrict__ outp, const float* __restrict__ addend,
    const float* __restrict__ hsrc, const float* __restrict__ diag,
    int N, int K, float escale)
{
    __shared__ unsigned short lsA[128 * 32];
    __shared__ unsigned short lsB[128 * 32];
    int tid = threadIdx.x, lane = tid & 63, wave = tid >> 6;
    int wm = wave >> 1, wn = wave & 1;
    int bm = blockIdx.y * 128, bn = blockIdx.x * 128;
    int lrow = lane >> 2, lcol = (lane & 3) * 8;

    f32x4 acc[4][4];
    #pragma unroll
    for (int i = 0; i < 4; ++i)
        #pragma unroll
        for (int j = 0; j < 4; ++j) {
            f32x4 z = {0.f, 0.f, 0.f, 0.f};
            acc[i][j] = z;
        }

    for (int k0 = 0; k0 < K; k0 += 32) {
        __syncthreads();
        #pragma unroll
        for (int r = 0; r < 2; ++r) {
            int row = r * 64 + wave * 16 + lrow;
            gld_lds16(A  + (size_t)(bm + row) * K + k0 + lcol, &lsA[row * 32 + lcol]);
            gld_lds16(Bt + (size_t)(bn + row) * K + k0 + lcol, &lsB[row * 32 + lcol]);
        }
        __syncthreads();
        int quad = lane >> 4, mr = lane & 15;
        bf16x8 av[4], bv[4];
        #pragma unroll
        for (int t2 = 0; t2 < 4; ++t2) {
            av[t2] = *(const bf16x8*)&lsA[(wm * 64 + t2 * 16 + mr) * 32 + quad * 8];
            bv[t2] = *(const bf16x8*)&lsB[(wn * 64 + t2 * 16 + mr) * 32 + quad * 8];
        }
        #pragma unroll
        for (int tm = 0; tm < 4; ++tm)
            #pragma unroll
            for (int tn = 0; tn < 4; ++tn)
                acc[tm][tn] = __builtin_amdgcn_mfma_f32_16x16x32_bf16(
                    av[tm], bv[tn], acc[tm][tn], 0, 0, 0);
    }

    int quad = lane >> 4, col = lane & 15;
    float* outf = (float*)outp;
    unsigned short* outb = (unsigned short*)outp;
    #pragma unroll
    for (int tm = 0; tm < 4; ++tm) {
        int gm0 = bm + wm * 64 + tm * 16 + quad * 4;
        #pragma unroll
        for (int tn = 0; tn < 4; ++tn) {
            int gn = bn + wn * 64 + tn * 16 + col;
            #pragma unroll
            for (int r = 0; r < 4; ++r) {
                float val = acc[tm][tn][r];
                if (EPI == 1) val *= escale;
                if (EPI == 2)
                    val = (fminf(val, 0.f) - log1pf(expf(-fabsf(val)))) * 0.0625f;
                size_t oi = (size_t)(gm0 + r) * N + gn;
                if (HASDIAG) val += hsrc[oi] * diag[gn];
                if (HASADD)  val += addend[oi];
                if (OUTBF) outb[oi] = f2bfu(val);
                else       outf[oi] = val;
            }
        }
    }
}

// ---------------------------------------------------------------------------
// Chunked GLA scan, phase C1: per (chunk, bh), per channel i:
//   c_t = cumsum(lg); q <- q*exp(c_t); k <- k*exp(-c_t); dLe = exp(c_L)
// ---------------------------------------------------------------------------
__global__ __launch_bounds__(128) void k_c1(
    const float* __restrict__ lg, unsigned short* __restrict__ q,
    unsigned short* __restrict__ kk, float* __restrict__ dLe)
{
    int chunk = blockIdx.x, bh = blockIdx.y;
    int b = bh >> 3, h = bh & 7;
    int i = threadIdx.x;
    size_t r0 = (size_t)b * TT + (size_t)chunk * LCH;
    float c = 0.f, e = 1.f;
    for (int t = 0; t < LCH; ++t) {
        size_t off = (r0 + t) * DKK + h * DKH + i;
        c += lg[off];
        e = __expf(c);
        float ei = __expf(-c);
        q[off] = f2bfu(bfu2f(q[off]) * e);
        kk[off] = f2bfu(bfu2f(kk[off]) * ei);
    }
    dLe[((size_t)chunk * 32 + bh) * DKH + i] = e;
}

// ---------------------------------------------------------------------------
// C2: per (chunk, bh): P = causal(Q~ K~^T);  O_intra = P V -> ob (bf16);
//     U = K~^T V -> fp32.  Dynamic LDS: 4 * 128*PADW shorts = 139264 B.
// ---------------------------------------------------------------------------
__global__ __launch_bounds__(256, 1) void k_c2(
    const unsigned short* __restrict__ q, const unsigned short* __restrict__ kk,
    const unsigned short* __restrict__ v, unsigned short* __restrict__ ob,
    float* __restrict__ U)
{
    extern __shared__ unsigned short sm[];
    unsigned short* lQ  = sm;                 // [t][i], later P [t][s]
    unsigned short* lK  = sm + LCH * PADW;    // [s][i]
    unsigned short* lKT = sm + 2 * LCH * PADW;// [i][s]
    unsigned short* lVT = sm + 3 * LCH * PADW;// [j][s] (one 128-wide j panel)

    int chunk = blockIdx.x, bh = blockIdx.y;
    int b = bh >> 3, h = bh & 7;
    int tid = threadIdx.x, lane = tid & 63, wave = tid >> 6;
    int wm = wave >> 1, wn = wave & 1;
    int quad = lane >> 4, mr = lane & 15;
    size_t r0 = (size_t)b * TT + (size_t)chunk * LCH;

    // stage Q~, K~ (row-major) and K~^T (scalar transpose writes)
    #pragma unroll
    for (int ps = 0; ps < 8; ++ps) {
        int idx = ps * 256 + tid;
        int row = idx >> 4, c8 = (idx & 15) * 8;
        size_t g = (r0 + row) * DKK + h * DKH + c8;
        *(int4*)&lQ[row * PADW + c8] = *(const int4*)&q[g];
        union { int4 w; unsigned short u[8]; } tmp;
        tmp.w = *(const int4*)&kk[g];
        *(int4*)&lK[row * PADW + c8] = tmp.w;
        #pragma unroll
        for (int u2 = 0; u2 < 8; ++u2)
            lKT[(c8 + u2) * PADW + row] = tmp.u[u2];
    }
    __syncthreads();

    // P = Q~ K~^T (each wave one 64x64 quadrant)
    f32x4 pa[4][4];
    #pragma unroll
    for (int i = 0; i < 4; ++i)
        #pragma unroll
        for (int j = 0; j < 4; ++j) { f32x4 z = {0,0,0,0}; pa[i][j] = z; }
    for (int k0 = 0; k0 < DKH; k0 += 32) {
        bf16x8 av[4], bv[4];
        #pragma unroll
        for (int t2 = 0; t2 < 4; ++t2) {
            av[t2] = *(const bf16x8*)&lQ[(wm * 64 + t2 * 16 + mr) * PADW + k0 + quad * 8];
            bv[t2] = *(const bf16x8*)&lK[(wn * 64 + t2 * 16 + mr) * PADW + k0 + quad * 8];
        }
        #pragma unroll
        for (int tm = 0; tm < 4; ++tm)
            #pragma unroll
            for (int tn = 0; tn < 4; ++tn)
                pa[tm][tn] = __builtin_amdgcn_mfma_f32_16x16x32_bf16(
                    av[tm], bv[tn], pa[tm][tn], 0, 0, 0);
    }
    __syncthreads();   // all reads of lQ done before overwrite

    // causal mask + write P (bf16) into lQ region as [t][s]; stage V^T panel 0
    #pragma unroll
    for (int tm = 0; tm < 4; ++tm)
        #pragma unroll
        for (int tn = 0; tn < 4; ++tn)
            #pragma unroll
            for (int r = 0; r < 4; ++r) {
                int trow = wm * 64 + tm * 16 + quad * 4 + r;
                int scol = wn * 64 + tn * 16 + mr;
                float pv = (trow >= scol) ? pa[tm][tn][r] : 0.f;
                lQ[trow * PADW + scol] = f2bfu(pv);
            }
    #pragma unroll
    for (int ps = 0; ps < 8; ++ps) {
        int idx = ps * 256 + tid;
        int s = idx >> 4, j8 = (idx & 15) * 8;
        size_t g = (r0 + s) * DVV + h * DVH + j8;   // panel 0
        union { int4 w; unsigned short u[8]; } tmp;
        tmp.w = *(const int4*)&v[g];
        #pragma unroll
        for (int u2 = 0; u2 < 8; ++u2)
            lVT[(j8 + u2) * PADW + s] = tmp.u[u2];
    }
    __syncthreads();

    #pragma unroll 1
    for (int panel = 0; panel < 2; ++panel) {
        f32x4 oa[4][4], ua[4][4];
        #pragma unroll
        for (int i = 0; i < 4; ++i)
            #pragma unroll
            for (int j = 0; j < 4; ++j) { f32x4 z = {0,0,0,0}; oa[i][j] = z; ua[i][j] = z; }
        for (int k0 = 0; k0 < LCH; k0 += 32) {
            bf16x8 pv[4], kt[4], vb[4];
            #pragma unroll
            for (int t2 = 0; t2 < 4; ++t2) {
                pv[t2] = *(const bf16x8*)&lQ [(wm * 64 + t2 * 16 + mr) * PADW + k0 + quad * 8];
                kt[t2] = *(const bf16x8*)&lKT[(wm * 64 + t2 * 16 + mr) * PADW + k0 + quad * 8];
                vb[t2] = *(const bf16x8*)&lVT[(wn * 64 + t2 * 16 + mr) * PADW + k0 + quad * 8];
            }
            #pragma unroll
            for (int tm = 0; tm < 4; ++tm)
                #pragma unroll
                for (int tn = 0; tn < 4; ++tn) {
                    oa[tm][tn] = __builtin_amdgcn_mfma_f32_16x16x32_bf16(
                        pv[tm], vb[tn], oa[tm][tn], 0, 0, 0);
                    ua[tm][tn] = __builtin_amdgcn_mfma_f32_16x16x32_bf16(
                        kt[tm], vb[tn], ua[tm][tn], 0, 0, 0);
                }
        }
        #pragma unroll
        for (int tm = 0; tm < 4; ++tm)
            #pragma unroll
            for (int tn = 0; tn < 4; ++tn)
                #pragma unroll
                for (int r = 0; r < 4; ++r) {
                    int m_ = wm * 64 + tm * 16 + quad * 4 + r;
                    int j_ = panel * 128 + wn * 64 + tn * 16 + mr;
                    ob[(r0 + m_) * DVV + h * DVH + j_] = f2bfu(oa[tm][tn][r]);
                    U[(((size_t)chunk * 32 + bh) * DKH + m_) * DVH + j_] = ua[tm][tn][r];
                }
        __syncthreads();
        if (panel == 0) {
            #pragma unroll
            for (int ps = 0; ps < 8; ++ps) {
                int idx = ps * 256 + tid;
                int s = idx >> 4, j8 = (idx & 15) * 8;
                size_t g = (r0 + s) * DVV + h * DVH + 128 + j8;   // panel 1
                union { int4 w; unsigned short u[8]; } tmp;
                tmp.w = *(const int4*)&v[g];
                #pragma unroll
                for (int u2 = 0; u2 < 8; ++u2)
                    lVT[(j8 + u2) * PADW + s] = tmp.u[u2];
            }
            __syncthreads();
        }
    }
}

// ---------------------------------------------------------------------------
// C3: sequential inter-chunk combine.  Thread owns (bh, i, j4); loops chunks:
//   read U_c, overwrite slot with S_c (state BEFORE chunk c), update
//   S <- dLe_c * (S + U_c).   In-place on U.
// ---------------------------------------------------------------------------
__global__ __launch_bounds__(256) void k_c3(
    float* __restrict__ U, const float* __restrict__ dLe)
{
    int gid = blockIdx.x * 256 + threadIdx.x;   // 262144 threads
    int bh = gid >> 13;
    int rem = gid & 8191;
    int i = rem >> 6, j4 = rem & 63;
    float4 S = make_float4(0.f, 0.f, 0.f, 0.f);
    for (int c = 0; c < NCH; ++c) {
        size_t off = (((size_t)c * 32 + bh) * DKH + i) * DVH + j4 * 4;
        float4 u = *(float4*)&U[off];
        *(float4*)&U[off] = S;
        float d = dLe[((size_t)c * 32 + bh) * DKH + i];
        S.x = d * (S.x + u.x); S.y = d * (S.y + u.y);
        S.z = d * (S.z + u.z); S.w = d * (S.w + u.w);
    }
}

// ---------------------------------------------------------------------------
// C4: inter-chunk output: ob += Q~ @ S_c.  S read fp32 from U slots,
// staged transposed to bf16 LDS.  Dynamic LDS: 2 * 128*PADW shorts = 69632 B.
// ---------------------------------------------------------------------------
__global__ __launch_bounds__(256, 1) void k_c4(
    const unsigned short* __restrict__ q, const float* __restrict__ S,
    unsigned short* __restrict__ ob)
{
    extern __shared__ unsigned short sm[];
    unsigned short* lQ  = sm;               // [t][i]
    unsigned short* lST = sm + LCH * PADW;  // [j][i]

    int chunk = blockIdx.x, bh = blockIdx.y;
    int b = bh >> 3, h = bh & 7;
    int tid = threadIdx.x, lane = tid & 63, wave = tid >> 6;
    int wm = wave >> 1, wn = wave & 1;
    int quad = lane >> 4, mr = lane & 15;
    size_t r0 = (size_t)b * TT + (size_t)chunk * LCH;

    #pragma unroll
    for (int ps = 0; ps < 8; ++ps) {
        int idx = ps * 256 + tid;
        int row = idx >> 4, c8 = (idx & 15) * 8;
        size_t g = (r0 + row) * DKK + h * DKH + c8;
        *(int4*)&lQ[row * PADW + c8] = *(const int4*)&q[g];
    }

    #pragma unroll 1
    for (int panel = 0; panel < 2; ++panel) {
        __syncthreads();
        #pragma unroll
        for (int ps = 0; ps < 16; ++ps) {
            int idx = ps * 256 + tid;
            int i = idx >> 5, j4 = idx & 31;
            float4 sv = *(const float4*)&S[(((size_t)chunk * 32 + bh) * DKH + i) * DVH
                                           + panel * 128 + j4 * 4];
            lST[(j4 * 4 + 0) * PADW + i] = f2bfu(sv.x);
            lST[(j4 * 4 + 1) * PADW + i] = f2bfu(sv.y);
            lST[(j4 * 4 + 2) * PADW + i] = f2bfu(sv.z);
            lST[(j4 * 4 + 3) * PADW + i] = f2bfu(sv.w);
        }
        __syncthreads();

        f32x4 oa[4][4];
        #pragma unroll
        for (int i = 0; i < 4; ++i)
            #pragma unroll
            for (int j = 0; j < 4; ++j) { f32x4 z = {0,0,0,0}; oa[i][j] = z; }
        for (int k0 = 0; k0 < DKH; k0 += 32) {
            bf16x8 av[4], bv[4];
            #pragma unroll
            for (int t2 = 0; t2 < 4; ++t2) {
                av[t2] = *(const bf16x8*)&lQ [(wm * 64 + t2 * 16 + mr) * PADW + k0 + quad * 8];
                bv[t2] = *(const bf16x8*)&lST[(wn * 64 + t2 * 16 + mr) * PADW + k0 + quad * 8];
            }
            #pragma unroll
            for (int tm = 0; tm < 4; ++tm)
                #pragma unroll
                for (int tn = 0; tn < 4; ++tn)
                    oa[tm][tn] = __builtin_amdgcn_mfma_f32_16x16x32_bf16(
                        av[tm], bv[tn], oa[tm][tn], 0, 0, 0);
        }
        #pragma unroll
        for (int tm = 0; tm < 4; ++tm)
            #pragma unroll
            for (int tn = 0; tn < 4; ++tn)
                #pragma unroll
                for (int r = 0; r < 4; ++r) {
                    int t_ = wm * 64 + tm * 16 + quad * 4 + r;
                    int j_ = panel * 128 + wn * 64 + tn * 16 + mr;
                    size_t oi = (r0 + t_) * DVV + h * DVH + j_;
                    ob[oi] = f2bfu(bfu2f(ob[oi]) + oa[tm][tn][r]);
                }
    }
}

// ---------------------------------------------------------------------------
// gate: o <- bf16( o * silu(xg) )
// ---------------------------------------------------------------------------
__global__ __launch_bounds__(256) void k_gate(
    unsigned short* __restrict__ o0, const unsigned short* __restrict__ xg)
{
    size_t i = ((size_t)blockIdx.x * 256 + threadIdx.x) * 8;
    union { int4 v; unsigned short u[8]; } A, G, R;
    A.v = *(const int4*)&o0[i];
    G.v = *(const int4*)&xg[i];
    #pragma unroll
    for (int j = 0; j < 8; ++j) {
        float ov = bfu2f(A.u[j]);
        float xf = bfu2f(G.u[j]);
        float sg = xf / (1.f + expf(-xf));
        R.u[j] = f2bfu(ov * sg);
    }
    *(int4*)&o0[i] = R.v;
}

// ---------------------------------------------------------------------------
// LoRA rank-16, fp32
// ---------------------------------------------------------------------------
__global__ __launch_bounds__(256) void k_lora1(
    const float* __restrict__ G, const float* __restrict__ A, float* __restrict__ tmp)
{
    int row = blockIdx.x * 4 + (threadIdx.x >> 6);
    int lane = threadIdx.x & 63;
    float acc[16];
    #pragma unroll
    for (int r = 0; r < 16; ++r) acc[r] = 0.f;
    const float* grow = G + (size_t)row * DD;
    for (int k2 = lane; k2 < DD; k2 += 64) {
        float g = grow[k2];
        const float4* ar = (const float4*)(A + k2 * 16);
        float4 a0 = ar[0], a1 = ar[1], a2 = ar[2], a3 = ar[3];
        acc[0] = fmaf(g, a0.x, acc[0]);  acc[1] = fmaf(g, a0.y, acc[1]);
        acc[2] = fmaf(g, a0.z, acc[2]);  acc[3] = fmaf(g, a0.w, acc[3]);
        acc[4] = fmaf(g, a1.x, acc[4]);  acc[5] = fmaf(g, a1.y, acc[5]);
        acc[6] = fmaf(g, a1.z, acc[6]);  acc[7] = fmaf(g, a1.w, acc[7]);
        acc[8] = fmaf(g, a2.x, acc[8]);  acc[9] = fmaf(g, a2.y, acc[9]);
        acc[10] = fmaf(g, a2.z, acc[10]); acc[11] = fmaf(g, a2.w, acc[11]);
        acc[12] = fmaf(g, a3.x, acc[12]); acc[13] = fmaf(g, a3.y, acc[13]);
        acc[14] = fmaf(g, a3.z, acc[14]); acc[15] = fmaf(g, a3.w, acc[15]);
    }
    #pragma unroll
    for (int off = 32; off >= 1; off >>= 1)
        #pragma unroll
        for (int r = 0; r < 16; ++r) acc[r] += __shfl_xor(acc[r], off);
    if (lane == 0) {
        #pragma unroll
        for (int r = 0; r < 16; ++r) tmp[(size_t)row * 16 + r] = acc[r];
    }
}

__global__ __launch_bounds__(256) void k_lora2(
    float* __restrict__ G, const float* __restrict__ tmp, const float* __restrict__ Bm)
{
    int row = blockIdx.x, tid = threadIdx.x;
    __shared__ float t16[16];
    if (tid < 16) t16[tid] = tmp[(size_t)row * 16 + tid];
    __syncthreads();
    size_t base = (size_t)row * DD + tid * 4;
    float4 acc = *(float4*)&G[base];
    #pragma unroll
    for (int r = 0; r < 16; ++r) {
        float tv = t16[r];
        float4 bv = *(const float4*)&Bm[r * DD + tid * 4];
        acc.x = fmaf(tv, bv.x, acc.x); acc.y = fmaf(tv, bv.y, acc.y);
        acc.z = fmaf(tv, bv.z, acc.z); acc.w = fmaf(tv, bv.w, acc.w);
    }
    *(float4*)&G[base] = acc;
}

// ---------------------------------------------------------------------------
// ACT halting (race-free via LDS staging)
// ---------------------------------------------------------------------------
__global__ __launch_bounds__(256) void k_act(
    const float* __restrict__ h, const float* __restrict__ act_w,
    const float* __restrict__ act_b, float* __restrict__ out,
    float* __restrict__ cum, int* __restrict__ halted)
{
    int row = blockIdx.x, tid = threadIdx.x;
    size_t base = (size_t)row * DD + tid * 4;
    float4 hv = *(const float4*)&h[base];
    float4 wv = *(const float4*)&act_w[tid * 4];
    float partial = hv.x*wv.x + hv.y*wv.y + hv.z*wv.z + hv.w*wv.w;
    __shared__ float red[256];
    __shared__ float s_cm;
    __shared__ int s_hl;
    if (tid == 0) { s_cm = cum[row]; s_hl = halted[row]; }
    red[tid] = partial; __syncthreads();
    for (int st = 128; st > 0; st >>= 1) {
        if (tid < st) red[tid] += red[tid + st];
        __syncthreads();
    }
    float p = 1.f / (1.f + expf(-(red[0] + act_b[0])));
    float cm = s_cm;
    int hl = s_hl;
    float p_eff = hl ? 0.f : p;
    float ncum = cm + p_eff;
    int newly = (!hl) && (ncum >= 0.99f);
    float w = newly ? (1.f - cm) : p_eff;
    float4 ho = *(float4*)&out[base];
    ho.x += w * hv.x; ho.y += w * hv.y; ho.z += w * hv.z; ho.w += w * hv.w;
    *(float4*)&out[base] = ho;
    if (tid == 0) { cum[row] = ncum; halted[row] = hl | newly; }
}

__global__ __launch_bounds__(256) void k_final(
    float* __restrict__ io, const float* __restrict__ w)
{
    int row = blockIdx.x, tid = threadIdx.x;
    size_t base = (size_t)row * DD + tid * 4;
    float4 hv = *(const float4*)&io[base];
    float partial = hv.x*hv.x + hv.y*hv.y + hv.z*hv.z + hv.w*hv.w;
    __shared__ float red[256];
    red[tid] = partial; __syncthreads();
    for (int st = 128; st > 0; st >>= 1) {
        if (tid < st) red[tid] += red[tid + st];
        __syncthreads();
    }
    float rms = rsqrtf(red[0] * (1.0f / DD) + 1e-6f);
    float4 wv = *(const float4*)&w[tid * 4];
    float4 o = make_float4(hv.x*rms*wv.x, hv.y*rms*wv.y, hv.z*rms*wv.z, hv.w*rms*wv.w);
    *(float4*)&io[base] = o;
}

// ---------------------------------------------------------------------------
extern "C" void kernel_launch(void* const* d_in, const int* in_sizes, int n_in,
                              void* d_out, int out_size, void* d_ws, size_t ws_size,
                              hipStream_t stream)
{
    const float* in_h       = (const float*)d_in[0];
    const float* in_e       = (const float*)d_in[1];
    const float* norm_w     = (const float*)d_in[2];
    const float* out_norm_w = (const float*)d_in[3];
    const float* Wq   = (const float*)d_in[4];
    const float* Wk   = (const float*)d_in[5];
    const float* Wv   = (const float*)d_in[6];
    const float* Wgk  = (const float*)d_in[7];
    const float* Wg   = (const float*)d_in[8];
    const float* Wo   = (const float*)d_in[9];
    const float* lora_A = (const float*)d_in[10];
    const float* lora_B = (const float*)d_in[11];
    const float* inj_A  = (const float*)d_in[12];
    const float* inj_B  = (const float*)d_in[13];
    const float* act_w  = (const float*)d_in[14];
    const float* act_b  = (const float*)d_in[15];
    const float* loop_table = (const float*)d_in[16];

    char* p;
    if (ws_size >= WS_NEED) {
        p = (char*)d_ws;
    } else {
        void* sym = nullptr;
        hipGetSymbolAddress(&sym, HIP_SYMBOL(g_ws));
        p = (char*)sym;
    }

    float* h      = (float*)p;            p += (size_t)MR * DD * 4;
    unsigned short* h_bf  = (unsigned short*)p; p += (size_t)MR * DD * 2;
    unsigned short* e_bf  = (unsigned short*)p; p += (size_t)MR * DD * 2;
    unsigned short* xn_bf = (unsigned short*)p; p += (size_t)MR * DD * 2;
    unsigned short* q_bf  = (unsigned short*)p; p += (size_t)MR * DKK * 2;
    unsigned short* k_bf  = (unsigned short*)p; p += (size_t)MR * DKK * 2;
    unsigned short* v_bf  = (unsigned short*)p; p += (size_t)MR * DVV * 2;
    float* lgbuf  = (float*)p;            p += (size_t)MR * DKK * 4;
    unsigned short* ob0   = (unsigned short*)p; p += (size_t)MR * DVV * 2;
    float* U      = (float*)p;            p += (size_t)NCH * 32 * DKH * DVH * 4; // 134 MB
    float* dLe    = (float*)p;            p += (size_t)NCH * 32 * DKH * 4;
    unsigned short* WqT  = (unsigned short*)p; p += (size_t)DKK * DD * 2;
    unsigned short* WkT  = (unsigned short*)p; p += (size_t)DKK * DD * 2;
    unsigned short* WgkT = (unsigned short*)p; p += (size_t)DKK * DD * 2;
    unsigned short* WvT  = (unsigned short*)p; p += (size_t)DVV * DD * 2;
    unsigned short* WgT  = (unsigned short*)p; p += (size_t)DVV * DD * 2;
    unsigned short* WoT  = (unsigned short*)p; p += (size_t)DD * DVV * 2;
    unsigned short* injA_bf = (unsigned short*)p; p += (size_t)DD * DD * 2;
    unsigned short* injB_bf = (unsigned short*)p; p += (size_t)DD * DD * 2;
    float* diagA = (float*)p;             p += DD * 4;
    float* tmp16 = (float*)p;             p += (size_t)MR * 16 * 4;
    float* cum   = (float*)p;             p += MR * 4;
    int*   halted = (int*)p;              p += MR * 4;
    // Aliases (lifetime-checked):
    unsigned short* xg_bf = q_bf;   // Wg GEMM runs AFTER C4; q~ dead then
    float* g2 = lgbuf;              // lg dead after C1
    float* t1 = (float*)ob0;        // ob0 dead after Wo GEMM
    float* h_out = (float*)d_out;

    hipMemcpyAsync(h, in_h, (size_t)MR * DD * 4, hipMemcpyDeviceToDevice, stream);
    hipMemsetAsync(h_out, 0, (size_t)MR * DD * 4, stream);
    hipMemsetAsync(cum, 0, MR * 4, stream);
    hipMemsetAsync(halted, 0, MR * 4, stream);

    k_transpose_bf16<<<dim3(16, 16), 256, 0, stream>>>(Wq,  WqT,  DD, DKK);
    k_transpose_bf16<<<dim3(16, 16), 256, 0, stream>>>(Wk,  WkT,  DD, DKK);
    k_transpose_bf16<<<dim3(16, 16), 256, 0, stream>>>(Wgk, WgkT, DD, DKK);
    k_transpose_bf16<<<dim3(32, 16), 256, 0, stream>>>(Wv,  WvT,  DD, DVV);
    k_transpose_bf16<<<dim3(32, 16), 256, 0, stream>>>(Wg,  WgT,  DD, DVV);
    k_transpose_bf16<<<dim3(16, 32), 256, 0, stream>>>(Wo,  WoT,  DVV, DD);
    k_conv_injA<<<4096, 256, 0, stream>>>(inj_A, injA_bf, diagA);
    k_convert_bf16<<<1024, 256, 0, stream>>>(inj_B, injB_bf);
    k_convert_bf16<<<MR * DD / 1024, 256, 0, stream>>>(in_e, e_bf);

    const float qscale = 0.08838834764831845f;   // 128^-0.5

    for (int t = 0; t < NLOOPS; ++t) {
        k_prep<<<MR, 256, 0, stream>>>(h, in_e, norm_w, loop_table + t * 128, h_bf, xn_bf);

        k_gemm<1,1,0,0><<<dim3(DKK/128, MR/128), 256, 0, stream>>>(
            xn_bf, WqT, q_bf, nullptr, nullptr, nullptr, DKK, DD, qscale);
        k_gemm<0,1,0,0><<<dim3(DKK/128, MR/128), 256, 0, stream>>>(
            xn_bf, WkT, k_bf, nullptr, nullptr, nullptr, DKK, DD, 1.f);
        k_gemm<2,0,0,0><<<dim3(DKK/128, MR/128), 256, 0, stream>>>(
            xn_bf, WgkT, lgbuf, nullptr, nullptr, nullptr, DKK, DD, 1.f);
        k_gemm<0,1,0,0><<<dim3(DVV/128, MR/128), 256, 0, stream>>>(
            xn_bf, WvT, v_bf, nullptr, nullptr, nullptr, DVV, DD, 1.f);

        // chunked GLA scan
        k_c1<<<dim3(NCH, 32), 128, 0, stream>>>(lgbuf, q_bf, k_bf, dLe);
        k_c2<<<dim3(NCH, 32), 256, 4 * LCH * PADW * 2, stream>>>(
            q_bf, k_bf, v_bf, ob0, U);
        k_c3<<<1024, 256, 0, stream>>>(U, dLe);
        k_c4<<<dim3(NCH, 32), 256, 2 * LCH * PADW * 2, stream>>>(q_bf, U, ob0);

        // Wg projection AFTER C4 so xg can reuse q space
        k_gemm<0,1,0,0><<<dim3(DVV/128, MR/128), 256, 0, stream>>>(
            xn_bf, WgT, xg_bf, nullptr, nullptr, nullptr, DVV, DD, 1.f);

        k_gate<<<(int)((size_t)MR * DVV / 2048), 256, 0, stream>>>(ob0, xg_bf);

        k_gemm<0,0,0,0><<<dim3(DD/128, MR/128), 256, 0, stream>>>(
            ob0, WoT, g2, nullptr, nullptr, nullptr, DD, DVV, 1.f);

        k_lora1<<<MR / 4, 256, 0, stream>>>(g2, lora_A + (size_t)t * DD * 16, tmp16);
        k_lora2<<<MR, 256, 0, stream>>>(g2, tmp16, lora_B + (size_t)t * 16 * DD);

        k_gemm<0,0,1,1><<<dim3(DD/128, MR/128), 256, 0, stream>>>(
            h_bf, injA_bf, t1, g2, h, diagA, DD, DD, 1.f);
        k_gemm<0,0,1,0><<<dim3(DD/128, MR/128), 256, 0, stream>>>(
            e_bf, injB_bf, h, t1, nullptr, nullptr, DD, DD, 1.f);

        k_act<<<MR, 256, 0, stream>>>(h, act_w, act_b, h_out, cum, halted);
    }

    k_final<<<MR, 256, 0, stream>>>(h_out, out_norm_w);
}

// Round 5
// 4834.121 us; speedup vs baseline: 1.8809x; 1.0440x over previous
//
#include <hip/hip_runtime.h>

// ---------------------------------------------------------------------------
// Problem constants (B=4, T=4096, D=1024, H=8, DK=1024, DV=2048, RANK=16,
// LOOPD=128, n_loops=4)
// ---------------------------------------------------------------------------
#define BB 4
#define TT 4096
#define DD 1024
#define HH 8
#define DKK 1024
#define DVV 2048
#define MR (BB*TT)          // 16384 rows
#define DKH 128
#define DVH 256
#define NLOOPS 4
#define LCH 128             // scan chunk length
#define NCH (TT/LCH)        // 32 chunks per batch
#define PADW 136            // LDS row stride (shorts) for scan kernels
#define NPROJ 7168          // q(1024) | k(1024) | lg(1024) | v(2048) | xg(2048)

// Total workspace need (bytes) for the layout in kernel_launch
#define WS_NEED 662310912ull

// Static fallback workspace (module-load allocated; used when ws_size < WS_NEED)
__device__ __attribute__((aligned(256))) unsigned char g_ws[WS_NEED];

typedef __bf16 bf16x8 __attribute__((ext_vector_type(8)));
typedef float  f32x4  __attribute__((ext_vector_type(4)));

// GEMM shared-memory: staging buffers for K-loop, then C-tile for epilogue
union GemmSmem {
    unsigned short ab[2][128 * 32];   // lsA / lsB (8 KB each)
    unsigned short c16[128 * 136];    // bf16 C tile, padded stride (34816 B)
    float cf[64 * 140];               // fp32 C half-tile, padded (35840 B)
};

__device__ __forceinline__ unsigned short f2bfu(float f) {
    unsigned int u = __builtin_bit_cast(unsigned int, f);
    u += 0x7fffu + ((u >> 16) & 1u);
    return (unsigned short)(u >> 16);
}
__device__ __forceinline__ float bfu2f(unsigned short s) {
    unsigned int u = ((unsigned int)s) << 16;
    return __builtin_bit_cast(float, u);
}

__device__ __forceinline__ void gld_lds16(const void* g, void* l) {
    __builtin_amdgcn_global_load_lds(
        (__attribute__((address_space(1))) void*)const_cast<void*>(g),
        (__attribute__((address_space(3))) void*)l, 16, 0, 0);
}

// ---------------------------------------------------------------------------
// Weight prep: fp32 [K][N] -> bf16 [N][K]  (B^T layout for the MFMA GEMM)
// ---------------------------------------------------------------------------
__global__ __launch_bounds__(256) void k_transpose_bf16(
    const float* __restrict__ in, unsigned short* __restrict__ out, int K, int N)
{
    __shared__ float tile[64][65];
    int k0 = blockIdx.y * 64, n0 = blockIdx.x * 64;
    int tx = threadIdx.x & 63, ty = threadIdx.x >> 6;
    #pragma unroll
    for (int r = 0; r < 64; r += 4)
        tile[ty + r][tx] = in[(size_t)(k0 + ty + r) * N + n0 + tx];
    __syncthreads();
    #pragma unroll
    for (int r = 0; r < 64; r += 4)
        out[(size_t)(n0 + ty + r) * K + k0 + tx] = f2bfu(tile[tx][ty + r]);
}

// e fp32 [MR][1024] -> bf16 into he[row][1024..2047]
__global__ __launch_bounds__(256) void k_conv_e(
    const float* __restrict__ e, unsigned short* __restrict__ he)
{
    size_t gid = (size_t)blockIdx.x * 256 + threadIdx.x;
    size_t b4 = gid * 4;
    size_t row = b4 >> 10; int col = (int)(b4 & 1023);
    float4 v = *(const float4*)&e[row * 1024 + col];
    *(ushort4*)&he[row * 2048 + 1024 + col] =
        make_ushort4(f2bfu(v.x), f2bfu(v.y), f2bfu(v.z), f2bfu(v.w));
}

// Combined injection weight: WinjT[n][0:1024]=injA[n][:] (diag zeroed,
// extracted), WinjT[n][1024:2048]=injB[n][:]
__global__ __launch_bounds__(256) void k_conv_injcomb(
    const float* __restrict__ injA, const float* __restrict__ injB,
    unsigned short* __restrict__ WinjT, float* __restrict__ diag)
{
    int idx = blockIdx.x * 256 + threadIdx.x;      // over 1024*1024
    int i = idx >> 10, j = idx & 1023;
    float va = injA[idx], vb = injB[idx];
    unsigned short ua;
    if (i == j) { diag[i] = va; ua = 0; }
    else        { ua = f2bfu(va); }
    WinjT[(size_t)i * 2048 + j] = ua;
    WinjT[(size_t)i * 2048 + 1024 + j] = f2bfu(vb);
}

// ---------------------------------------------------------------------------
// prep: h[:, :128] += loop_table[t]; xn = rmsnorm(h+e)*w -> bf16;
//       he[row][0:1024] = bf16(h)
// ---------------------------------------------------------------------------
__global__ __launch_bounds__(256) void k_prep(
    float* __restrict__ h, const float* __restrict__ e,
    const float* __restrict__ norm_w, const float* __restrict__ ltab,
    unsigned short* __restrict__ he, unsigned short* __restrict__ xn_bf)
{
    int row = blockIdx.x, tid = threadIdx.x;
    size_t base = (size_t)row * DD + tid * 4;
    float4 hv = *(float4*)&h[base];
    if (tid < 32) {
        float4 lv = *(const float4*)&ltab[tid * 4];
        hv.x += lv.x; hv.y += lv.y; hv.z += lv.z; hv.w += lv.w;
        *(float4*)&h[base] = hv;
    }
    float4 ev = *(const float4*)&e[base];
    float sx = hv.x + ev.x, sy = hv.y + ev.y, sz = hv.z + ev.z, sw = hv.w + ev.w;
    float partial = sx*sx + sy*sy + sz*sz + sw*sw;
    __shared__ float red[256];
    red[tid] = partial; __syncthreads();
    for (int st = 128; st > 0; st >>= 1) {
        if (tid < st) red[tid] += red[tid + st];
        __syncthreads();
    }
    float rms = rsqrtf(red[0] * (1.0f / DD) + 1e-6f);
    float4 wv = *(const float4*)&norm_w[tid * 4];
    *(ushort4*)&xn_bf[base] = make_ushort4(
        f2bfu(sx * rms * wv.x), f2bfu(sy * rms * wv.y),
        f2bfu(sz * rms * wv.z), f2bfu(sw * rms * wv.w));
    *(ushort4*)&he[(size_t)row * 2048 + tid * 4] =
        make_ushort4(f2bfu(hv.x), f2bfu(hv.y), f2bfu(hv.z), f2bfu(hv.w));
}

// ---------------------------------------------------------------------------
// Fused projection GEMM: A[MR,1024] @ WprojT[7168,1024]^T.
// Output ranges (block-uniform): [0,1024) q*qscale bf16; [1024,2048) k bf16;
// [2048,3072) lg=logsigmoid/16 fp32; [3072,5120) v bf16; [5120,7168) xg bf16.
// LDS-staged coalesced C writes.
// ---------------------------------------------------------------------------
__global__ __launch_bounds__(256) void k_gemm_proj(
    const unsigned short* __restrict__ A, const unsigned short* __restrict__ Bt,
    unsigned short* __restrict__ qout, unsigned short* __restrict__ kout,
    float* __restrict__ lgout, unsigned short* __restrict__ vout,
    unsigned short* __restrict__ xgout, float qscale)
{
    __shared__ GemmSmem sm;
    unsigned short* lsA = sm.ab[0];
    unsigned short* lsB = sm.ab[1];
    int tid = threadIdx.x, lane = tid & 63, wave = tid >> 6;
    int wm = wave >> 1, wn = wave & 1;
    int bm = blockIdx.y * 128, bn = blockIdx.x * 128;
    int lrow = lane >> 2, lcol = (lane & 3) * 8;
    const int K = 1024;

    f32x4 acc[4][4];
    #pragma unroll
    for (int i = 0; i < 4; ++i)
        #pragma unroll
        for (int j = 0; j < 4; ++j) { f32x4 z = {0,0,0,0}; acc[i][j] = z; }

    for (int k0 = 0; k0 < K; k0 += 32) {
        __syncthreads();
        #pragma unroll
        for (int r = 0; r < 2; ++r) {
            int row = r * 64 + wave * 16 + lrow;
            gld_lds16(A  + (size_t)(bm + row) * K + k0 + lcol, &lsA[row * 32 + lcol]);
            gld_lds16(Bt + (size_t)(bn + row) * K + k0 + lcol, &lsB[row * 32 + lcol]);
        }
        __syncthreads();
        int quad = lane >> 4, mr = lane & 15;
        bf16x8 av[4], bv[4];
        #pragma unroll
        for (int t2 = 0; t2 < 4; ++t2) {
            av[t2] = *(const bf16x8*)&lsA[(wm * 64 + t2 * 16 + mr) * 32 + quad * 8];
            bv[t2] = *(const bf16x8*)&lsB[(wn * 64 + t2 * 16 + mr) * 32 + quad * 8];
        }
        #pragma unroll
        for (int tm = 0; tm < 4; ++tm)
            #pragma unroll
            for (int tn = 0; tn < 4; ++tn)
                acc[tm][tn] = __builtin_amdgcn_mfma_f32_16x16x32_bf16(
                    av[tm], bv[tn], acc[tm][tn], 0, 0, 0);
    }

    int quad = lane >> 4, mr = lane & 15;
    __syncthreads();   // all LDS staging reads done before C-tile reuse

    if (bn >= 2048 && bn < 3072) {
        // lg fp32, 2-pass staged epilogue
        int cb = bn - 2048;
        #pragma unroll 1
        for (int half = 0; half < 2; ++half) {
            if (wm == half) {
                #pragma unroll
                for (int tm = 0; tm < 4; ++tm)
                    #pragma unroll
                    for (int tn = 0; tn < 4; ++tn)
                        #pragma unroll
                        for (int r = 0; r < 4; ++r) {
                            float v = acc[tm][tn][r];
                            v = (fminf(v, 0.f) - log1pf(expf(-fabsf(v)))) * 0.0625f;
                            sm.cf[(tm * 16 + quad * 4 + r) * 140 + wn * 64 + tn * 16 + mr] = v;
                        }
            }
            __syncthreads();
            #pragma unroll
            for (int ps = 0; ps < 8; ++ps) {
                int idx = ps * 256 + tid;
                int rl = idx >> 5, c4 = (idx & 31) * 4;
                float4 vv = *(float4*)&sm.cf[rl * 140 + c4];
                *(float4*)&lgout[(size_t)(bm + half * 64 + rl) * 1024 + cb + c4] = vv;
            }
            __syncthreads();
        }
    } else {
        unsigned short* obuf; int stride, cb;
        float scale = 1.f;
        if (bn < 1024)      { obuf = qout;  stride = 1024; cb = bn;        scale = qscale; }
        else if (bn < 2048) { obuf = kout;  stride = 1024; cb = bn - 1024; }
        else if (bn < 5120) { obuf = vout;  stride = 2048; cb = bn - 3072; }
        else                { obuf = xgout; stride = 2048; cb = bn - 5120; }
        #pragma unroll
        for (int tm = 0; tm < 4; ++tm)
            #pragma unroll
            for (int tn = 0; tn < 4; ++tn)
                #pragma unroll
                for (int r = 0; r < 4; ++r)
                    sm.c16[(wm * 64 + tm * 16 + quad * 4 + r) * 136
                           + wn * 64 + tn * 16 + mr] = f2bfu(acc[tm][tn][r] * scale);
        __syncthreads();
        #pragma unroll
        for (int ps = 0; ps < 8; ++ps) {
            int idx = ps * 256 + tid;
            int rl = idx >> 4, c8 = (idx & 15) * 8;
            int4 w = *(int4*)&sm.c16[rl * 136 + c8];
            *(int4*)&obuf[(size_t)(bm + rl) * stride + cb + c8] = w;
        }
    }
}

// ---------------------------------------------------------------------------
// fp32-output GEMM (Wo / injection), LDS-staged 2-pass epilogue.
// HASADD: += addend[oi]; HASDIAG: += hsrc[oi]*diag[col] (in-place-safe).
// ---------------------------------------------------------------------------
template<int HASADD, int HASDIAG>
__global__ __launch_bounds__(256) void k_gemm_f32(
    const unsigned short* __restrict__ A, const unsigned short* __restrict__ Bt,
    float* __restrict__ out, const float* __restrict__ addend,
    const float* __restrict__ hsrc, const float* __restrict__ diag,
    int N, int K)
{
    __shared__ GemmSmem sm;
    unsigned short* lsA = sm.ab[0];
    unsigned short* lsB = sm.ab[1];
    int tid = threadIdx.x, lane = tid & 63, wave = tid >> 6;
    int wm = wave >> 1, wn = wave & 1;
    int bm = blockIdx.y * 128, bn = blockIdx.x * 128;
    int lrow = lane >> 2, lcol = (lane & 3) * 8;

    f32x4 acc[4][4];
    #pragma unroll
    for (int i = 0; i < 4; ++i)
        #pragma unroll
        for (int j = 0; j < 4; ++j) { f32x4 z = {0,0,0,0}; acc[i][j] = z; }

    for (int k0 = 0; k0 < K; k0 += 32) {
        __syncthreads();
        #pragma unroll
        for (int r = 0; r < 2; ++r) {
            int row = r * 64 + wave * 16 + lrow;
            gld_lds16(A  + (size_t)(bm + row) * K + k0 + lcol, &lsA[row * 32 + lcol]);
            gld_lds16(Bt + (size_t)(bn + row) * K + k0 + lcol, &lsB[row * 32 + lcol]);
        }
        __syncthreads();
        int quad = lane >> 4, mr = lane & 15;
        bf16x8 av[4], bv[4];
        #pragma unroll
        for (int t2 = 0; t2 < 4; ++t2) {
            av[t2] = *(const bf16x8*)&lsA[(wm * 64 + t2 * 16 + mr) * 32 + quad * 8];
            bv[t2] = *(const bf16x8*)&lsB[(wn * 64 + t2 * 16 + mr) * 32 + quad * 8];
        }
        #pragma unroll
        for (int tm = 0; tm < 4; ++tm)
            #pragma unroll
            for (int tn = 0; tn < 4; ++tn)
                acc[tm][tn] = __builtin_amdgcn_mfma_f32_16x16x32_bf16(
                    av[tm], bv[tn], acc[tm][tn], 0, 0, 0);
    }

    int quad = lane >> 4, mr = lane & 15;
    __syncthreads();
    #pragma unroll 1
    for (int half = 0; half < 2; ++half) {
        if (wm == half) {
            #pragma unroll
            for (int tm = 0; tm < 4; ++tm)
                #pragma unroll
                for (int tn = 0; tn < 4; ++tn)
                    #pragma unroll
                    for (int r = 0; r < 4; ++r)
                        sm.cf[(tm * 16 + quad * 4 + r) * 140
                              + wn * 64 + tn * 16 + mr] = acc[tm][tn][r];
        }
        __syncthreads();
        #pragma unroll
        for (int ps = 0; ps < 8; ++ps) {
            int idx = ps * 256 + tid;
            int rl = idx >> 5, c4 = (idx & 31) * 4;
            float4 vv = *(float4*)&sm.cf[rl * 140 + c4];
            size_t oi = (size_t)(bm + half * 64 + rl) * N + bn + c4;
            if (HASDIAG) {
                float4 hh = *(const float4*)&hsrc[oi];
                float4 dd = *(const float4*)&diag[bn + c4];
                vv.x += hh.x * dd.x; vv.y += hh.y * dd.y;
                vv.z += hh.z * dd.z; vv.w += hh.w * dd.w;
            }
            if (HASADD) {
                float4 aa = *(const float4*)&addend[oi];
                vv.x += aa.x; vv.y += aa.y; vv.z += aa.z; vv.w += aa.w;
            }
            *(float4*)&out[oi] = vv;
        }
        __syncthreads();
    }
}

// ---------------------------------------------------------------------------
// Chunked GLA scan, phase C1: per (chunk, bh), per channel i:
//   c_t = cumsum(lg); q <- q*exp(c_t); k <- k*exp(-c_t); dLe = exp(c_L)
// ---------------------------------------------------------------------------
__global__ __launch_bounds__(128) void k_c1(
    const float* __restrict__ lg, unsigned short* __restrict__ q,
    unsigned short* __restrict__ kk, float* __restrict__ dLe)
{
    int chunk = blockIdx.x, bh = blockIdx.y;
    int b = bh >> 3, h = bh & 7;
    int i = threadIdx.x;
    size_t r0 = (size_t)b * TT + (size_t)chunk * LCH;
    float c = 0.f, e = 1.f;
    for (int t = 0; t < LCH; ++t) {
        size_t off = (r0 + t) * DKK + h * DKH + i;
        c += lg[off];
        e = __expf(c);
        float ei = __expf(-c);
        q[off] = f2bfu(bfu2f(q[off]) * e);
        kk[off] = f2bfu(bfu2f(kk[off]) * ei);
    }
    dLe[((size_t)chunk * 32 + bh) * DKH + i] = e;
}

// ---------------------------------------------------------------------------
// C2: per (chunk, bh): P = causal(Q~ K~^T);  O_intra = P V -> ob (bf16);
//     U = K~^T V -> fp32.  Dynamic LDS: 4 * 128*PADW shorts = 139264 B.
// ---------------------------------------------------------------------------
__global__ __launch_bounds__(256, 1) void k_c2(
    const unsigned short* __restrict__ q, const unsigned short* __restrict__ kk,
    const unsigned short* __restrict__ v, unsigned short* __restrict__ ob,
    float* __restrict__ U)
{
    extern __shared__ unsigned short smd[];
    unsigned short* lQ  = smd;                 // [t][i], later P [t][s]
    unsigned short* lK  = smd + LCH * PADW;    // [s][i]
    unsigned short* lKT = smd + 2 * LCH * PADW;// [i][s]
    unsigned short* lVT = smd + 3 * LCH * PADW;// [j][s] (one 128-wide j panel)

    int chunk = blockIdx.x, bh = blockIdx.y;
    int b = bh >> 3, h = bh & 7;
    int tid = threadIdx.x, lane = tid & 63, wave = tid >> 6;
    int wm = wave >> 1, wn = wave & 1;
    int quad = lane >> 4, mr = lane & 15;
    size_t r0 = (size_t)b * TT + (size_t)chunk * LCH;

    #pragma unroll
    for (int ps = 0; ps < 8; ++ps) {
        int idx = ps * 256 + tid;
        int row = idx >> 4, c8 = (idx & 15) * 8;
        size_t g = (r0 + row) * DKK + h * DKH + c8;
        *(int4*)&lQ[row * PADW + c8] = *(const int4*)&q[g];
        union { int4 w; unsigned short u[8]; } tmp;
        tmp.w = *(const int4*)&kk[g];
        *(int4*)&lK[row * PADW + c8] = tmp.w;
        #pragma unroll
        for (int u2 = 0; u2 < 8; ++u2)
            lKT[(c8 + u2) * PADW + row] = tmp.u[u2];
    }
    __syncthreads();

    f32x4 pa[4][4];
    #pragma unroll
    for (int i = 0; i < 4; ++i)
        #pragma unroll
        for (int j = 0; j < 4; ++j) { f32x4 z = {0,0,0,0}; pa[i][j] = z; }
    for (int k0 = 0; k0 < DKH; k0 += 32) {
        bf16x8 av[4], bv[4];
        #pragma unroll
        for (int t2 = 0; t2 < 4; ++t2) {
            av[t2] = *(const bf16x8*)&lQ[(wm * 64 + t2 * 16 + mr) * PADW + k0 + quad * 8];
            bv[t2] = *(const bf16x8*)&lK[(wn * 64 + t2 * 16 + mr) * PADW + k0 + quad * 8];
        }
        #pragma unroll
        for (int tm = 0; tm < 4; ++tm)
            #pragma unroll
            for (int tn = 0; tn < 4; ++tn)
                pa[tm][tn] = __builtin_amdgcn_mfma_f32_16x16x32_bf16(
                    av[tm], bv[tn], pa[tm][tn], 0, 0, 0);
    }
    __syncthreads();

    #pragma unroll
    for (int tm = 0; tm < 4; ++tm)
        #pragma unroll
        for (int tn = 0; tn < 4; ++tn)
            #pragma unroll
            for (int r = 0; r < 4; ++r) {
                int trow = wm * 64 + tm * 16 + quad * 4 + r;
                int scol = wn * 64 + tn * 16 + mr;
                float pv = (trow >= scol) ? pa[tm][tn][r] : 0.f;
                lQ[trow * PADW + scol] = f2bfu(pv);
            }
    #pragma unroll
    for (int ps = 0; ps < 8; ++ps) {
        int idx = ps * 256 + tid;
        int s = idx >> 4, j8 = (idx & 15) * 8;
        size_t g = (r0 + s) * DVV + h * DVH + j8;   // panel 0
        union { int4 w; unsigned short u[8]; } tmp;
        tmp.w = *(const int4*)&v[g];
        #pragma unroll
        for (int u2 = 0; u2 < 8; ++u2)
            lVT[(j8 + u2) * PADW + s] = tmp.u[u2];
    }
    __syncthreads();

    #pragma unroll 1
    for (int panel = 0; panel < 2; ++panel) {
        f32x4 oa[4][4], ua[4][4];
        #pragma unroll
        for (int i = 0; i < 4; ++i)
            #pragma unroll
            for (int j = 0; j < 4; ++j) { f32x4 z = {0,0,0,0}; oa[i][j] = z; ua[i][j] = z; }
        for (int k0 = 0; k0 < LCH; k0 += 32) {
            bf16x8 pv[4], kt[4], vb[4];
            #pragma unroll
            for (int t2 = 0; t2 < 4; ++t2) {
                pv[t2] = *(const bf16x8*)&lQ [(wm * 64 + t2 * 16 + mr) * PADW + k0 + quad * 8];
                kt[t2] = *(const bf16x8*)&lKT[(wm * 64 + t2 * 16 + mr) * PADW + k0 + quad * 8];
                vb[t2] = *(const bf16x8*)&lVT[(wn * 64 + t2 * 16 + mr) * PADW + k0 + quad * 8];
            }
            #pragma unroll
            for (int tm = 0; tm < 4; ++tm)
                #pragma unroll
                for (int tn = 0; tn < 4; ++tn) {
                    oa[tm][tn] = __builtin_amdgcn_mfma_f32_16x16x32_bf16(
                        pv[tm], vb[tn], oa[tm][tn], 0, 0, 0);
                    ua[tm][tn] = __builtin_amdgcn_mfma_f32_16x16x32_bf16(
                        kt[tm], vb[tn], ua[tm][tn], 0, 0, 0);
                }
        }
        #pragma unroll
        for (int tm = 0; tm < 4; ++tm)
            #pragma unroll
            for (int tn = 0; tn < 4; ++tn)
                #pragma unroll
                for (int r = 0; r < 4; ++r) {
                    int m_ = wm * 64 + tm * 16 + quad * 4 + r;
                    int j_ = panel * 128 + wn * 64 + tn * 16 + mr;
                    ob[(r0 + m_) * DVV + h * DVH + j_] = f2bfu(oa[tm][tn][r]);
                    U[(((size_t)chunk * 32 + bh) * DKH + m_) * DVH + j_] = ua[tm][tn][r];
                }
        __syncthreads();
        if (panel == 0) {
            #pragma unroll
            for (int ps = 0; ps < 8; ++ps) {
                int idx = ps * 256 + tid;
                int s = idx >> 4, j8 = (idx & 15) * 8;
                size_t g = (r0 + s) * DVV + h * DVH + 128 + j8;   // panel 1
                union { int4 w; unsigned short u[8]; } tmp;
                tmp.w = *(const int4*)&v[g];
                #pragma unroll
                for (int u2 = 0; u2 < 8; ++u2)
                    lVT[(j8 + u2) * PADW + s] = tmp.u[u2];
            }
            __syncthreads();
        }
    }
}

// ---------------------------------------------------------------------------
// C3: sequential inter-chunk combine (in-place on U; U slot becomes S_c)
// ---------------------------------------------------------------------------
__global__ __launch_bounds__(256) void k_c3(
    float* __restrict__ U, const float* __restrict__ dLe)
{
    int gid = blockIdx.x * 256 + threadIdx.x;   // 262144 threads
    int bh = gid >> 13;
    int rem = gid & 8191;
    int i = rem >> 6, j4 = rem & 63;
    float4 S = make_float4(0.f, 0.f, 0.f, 0.f);
    for (int c = 0; c < NCH; ++c) {
        size_t off = (((size_t)c * 32 + bh) * DKH + i) * DVH + j4 * 4;
        float4 u = *(float4*)&U[off];
        *(float4*)&U[off] = S;
        float d = dLe[((size_t)c * 32 + bh) * DKH + i];
        S.x = d * (S.x + u.x); S.y = d * (S.y + u.y);
        S.z = d * (S.z + u.z); S.w = d * (S.w + u.w);
    }
}

// ---------------------------------------------------------------------------
// C4: ob = (ob_intra + Q~ @ S_c) * silu(xg)   (gate fused)
// Dynamic LDS: 2 * 128*PADW shorts = 69632 B.
// ---------------------------------------------------------------------------
__global__ __launch_bounds__(256, 1) void k_c4(
    const unsigned short* __restrict__ q, const float* __restrict__ S,
    unsigned short* __restrict__ ob, const unsigned short* __restrict__ xg)
{
    extern __shared__ unsigned short smd[];
    unsigned short* lQ  = smd;               // [t][i]
    unsigned short* lST = smd + LCH * PADW;  // [j][i]

    int chunk = blockIdx.x, bh = blockIdx.y;
    int b = bh >> 3, h = bh & 7;
    int tid = threadIdx.x, lane = tid & 63, wave = tid >> 6;
    int wm = wave >> 1, wn = wave & 1;
    int quad = lane >> 4, mr = lane & 15;
    size_t r0 = (size_t)b * TT + (size_t)chunk * LCH;

    #pragma unroll
    for (int ps = 0; ps < 8; ++ps) {
        int idx = ps * 256 + tid;
        int row = idx >> 4, c8 = (idx & 15) * 8;
        size_t g = (r0 + row) * DKK + h * DKH + c8;
        *(int4*)&lQ[row * PADW + c8] = *(const int4*)&q[g];
    }

    #pragma unroll 1
    for (int panel = 0; panel < 2; ++panel) {
        __syncthreads();
        #pragma unroll
        for (int ps = 0; ps < 16; ++ps) {
            int idx = ps * 256 + tid;
            int i = idx >> 5, j4 = idx & 31;
            float4 sv = *(const float4*)&S[(((size_t)chunk * 32 + bh) * DKH + i) * DVH
                                           + panel * 128 + j4 * 4];
            lST[(j4 * 4 + 0) * PADW + i] = f2bfu(sv.x);
            lST[(j4 * 4 + 1) * PADW + i] = f2bfu(sv.y);
            lST[(j4 * 4 + 2) * PADW + i] = f2bfu(sv.z);
            lST[(j4 * 4 + 3) * PADW + i] = f2bfu(sv.w);
        }
        __syncthreads();

        f32x4 oa[4][4];
        #pragma unroll
        for (int i = 0; i < 4; ++i)
            #pragma unroll
            for (int j = 0; j < 4; ++j) { f32x4 z = {0,0,0,0}; oa[i][j] = z; }
        for (int k0 = 0; k0 < DKH; k0 += 32) {
            bf16x8 av[4], bv[4];
            #pragma unroll
            for (int t2 = 0; t2 < 4; ++t2) {
                av[t2] = *(const bf16x8*)&lQ [(wm * 64 + t2 * 16 + mr) * PADW + k0 + quad * 8];
                bv[t2] = *(const bf16x8*)&lST[(wn * 64 + t2 * 16 + mr) * PADW + k0 + quad * 8];
            }
            #pragma unroll
            for (int tm = 0; tm < 4; ++tm)
                #pragma unroll
                for (int tn = 0; tn < 4; ++tn)
                    oa[tm][tn] = __builtin_amdgcn_mfma_f32_16x16x32_bf16(
                        av[tm], bv[tn], oa[tm][tn], 0, 0, 0);
        }
        #pragma unroll
        for (int tm = 0; tm < 4; ++tm)
            #pragma unroll
            for (int tn = 0; tn < 4; ++tn)
                #pragma unroll
                for (int r = 0; r < 4; ++r) {
                    int t_ = wm * 64 + tm * 16 + quad * 4 + r;
                    int j_ = panel * 128 + wn * 64 + tn * 16 + mr;
                    size_t oi = (r0 + t_) * DVV + h * DVH + j_;
                    float ov = bfu2f(ob[oi]) + oa[tm][tn][r];
                    float xf = bfu2f(xg[oi]);
                    ob[oi] = f2bfu(ov * xf / (1.f + expf(-xf)));
                }
    }
}

// ---------------------------------------------------------------------------
// LoRA rank-16, fp32
// ---------------------------------------------------------------------------
__global__ __launch_bounds__(256) void k_lora1(
    const float* __restrict__ G, const float* __restrict__ A, float* __restrict__ tmp)
{
    int row = blockIdx.x * 4 + (threadIdx.x >> 6);
    int lane = threadIdx.x & 63;
    float acc[16];
    #pragma unroll
    for (int r = 0; r < 16; ++r) acc[r] = 0.f;
    const float* grow = G + (size_t)row * DD;
    for (int k2 = lane; k2 < DD; k2 += 64) {
        float g = grow[k2];
        const float4* ar = (const float4*)(A + k2 * 16);
        float4 a0 = ar[0], a1 = ar[1], a2 = ar[2], a3 = ar[3];
        acc[0] = fmaf(g, a0.x, acc[0]);  acc[1] = fmaf(g, a0.y, acc[1]);
        acc[2] = fmaf(g, a0.z, acc[2]);  acc[3] = fmaf(g, a0.w, acc[3]);
        acc[4] = fmaf(g, a1.x, acc[4]);  acc[5] = fmaf(g, a1.y, acc[5]);
        acc[6] = fmaf(g, a1.z, acc[6]);  acc[7] = fmaf(g, a1.w, acc[7]);
        acc[8] = fmaf(g, a2.x, acc[8]);  acc[9] = fmaf(g, a2.y, acc[9]);
        acc[10] = fmaf(g, a2.z, acc[10]); acc[11] = fmaf(g, a2.w, acc[11]);
        acc[12] = fmaf(g, a3.x, acc[12]); acc[13] = fmaf(g, a3.y, acc[13]);
        acc[14] = fmaf(g, a3.z, acc[14]); acc[15] = fmaf(g, a3.w, acc[15]);
    }
    #pragma unroll
    for (int off = 32; off >= 1; off >>= 1)
        #pragma unroll
        for (int r = 0; r < 16; ++r) acc[r] += __shfl_xor(acc[r], off);
    if (lane == 0) {
        #pragma unroll
        for (int r = 0; r < 16; ++r) tmp[(size_t)row * 16 + r] = acc[r];
    }
}

__global__ __launch_bounds__(256) void k_lora2(
    float* __restrict__ G, const float* __restrict__ tmp, const float* __restrict__ Bm)
{
    int row = blockIdx.x, tid = threadIdx.x;
    __shared__ float t16[16];
    if (tid < 16) t16[tid] = tmp[(size_t)row * 16 + tid];
    __syncthreads();
    size_t base = (size_t)row * DD + tid * 4;
    float4 acc = *(float4*)&G[base];
    #pragma unroll
    for (int r = 0; r < 16; ++r) {
        float tv = t16[r];
        float4 bv = *(const float4*)&Bm[r * DD + tid * 4];
        acc.x = fmaf(tv, bv.x, acc.x); acc.y = fmaf(tv, bv.y, acc.y);
        acc.z = fmaf(tv, bv.z, acc.z); acc.w = fmaf(tv, bv.w, acc.w);
    }
    *(float4*)&G[base] = acc;
}

// ---------------------------------------------------------------------------
// ACT halting (race-free via LDS staging)
// ---------------------------------------------------------------------------
__global__ __launch_bounds__(256) void k_act(
    const float* __restrict__ h, const float* __restrict__ act_w,
    const float* __restrict__ act_b, float* __restrict__ out,
    float* __restrict__ cum, int* __restrict__ halted)
{
    int row = blockIdx.x, tid = threadIdx.x;
    size_t base = (size_t)row * DD + tid * 4;
    float4 hv = *(const float4*)&h[base];
    float4 wv = *(const float4*)&act_w[tid * 4];
    float partial = hv.x*wv.x + hv.y*wv.y + hv.z*wv.z + hv.w*wv.w;
    __shared__ float red[256];
    __shared__ float s_cm;
    __shared__ int s_hl;
    if (tid == 0) { s_cm = cum[row]; s_hl = halted[row]; }
    red[tid] = partial; __syncthreads();
    for (int st = 128; st > 0; st >>= 1) {
        if (tid < st) red[tid] += red[tid + st];
        __syncthreads();
    }
    float p = 1.f / (1.f + expf(-(red[0] + act_b[0])));
    float cm = s_cm;
    int hl = s_hl;
    float p_eff = hl ? 0.f : p;
    float ncum = cm + p_eff;
    int newly = (!hl) && (ncum >= 0.99f);
    float w = newly ? (1.f - cm) : p_eff;
    float4 ho = *(float4*)&out[base];
    ho.x += w * hv.x; ho.y += w * hv.y; ho.z += w * hv.z; ho.w += w * hv.w;
    *(float4*)&out[base] = ho;
    if (tid == 0) { cum[row] = ncum; halted[row] = hl | newly; }
}

__global__ __launch_bounds__(256) void k_final(
    float* __restrict__ io, const float* __restrict__ w)
{
    int row = blockIdx.x, tid = threadIdx.x;
    size_t base = (size_t)row * DD + tid * 4;
    float4 hv = *(const float4*)&io[base];
    float partial = hv.x*hv.x + hv.y*hv.y + hv.z*hv.z + hv.w*hv.w;
    __shared__ float red[256];
    red[tid] = partial; __syncthreads();
    for (int st = 128; st > 0; st >>= 1) {
        if (tid < st) red[tid] += red[tid + st];
        __syncthreads();
    }
    float rms = rsqrtf(red[0] * (1.0f / DD) + 1e-6f);
    float4 wv = *(const float4*)&w[tid * 4];
    float4 o = make_float4(hv.x*rms*wv.x, hv.y*rms*wv.y, hv.z*rms*wv.z, hv.w*rms*wv.w);
    *(float4*)&io[base] = o;
}

// ---------------------------------------------------------------------------
extern "C" void kernel_launch(void* const* d_in, const int* in_sizes, int n_in,
                              void* d_out, int out_size, void* d_ws, size_t ws_size,
                              hipStream_t stream)
{
    const float* in_h       = (const float*)d_in[0];
    const float* in_e       = (const float*)d_in[1];
    const float* norm_w     = (const float*)d_in[2];
    const float* out_norm_w = (const float*)d_in[3];
    const float* Wq   = (const float*)d_in[4];
    const float* Wk   = (const float*)d_in[5];
    const float* Wv   = (const float*)d_in[6];
    const float* Wgk  = (const float*)d_in[7];
    const float* Wg   = (const float*)d_in[8];
    const float* Wo   = (const float*)d_in[9];
    const float* lora_A = (const float*)d_in[10];
    const float* lora_B = (const float*)d_in[11];
    const float* inj_A  = (const float*)d_in[12];
    const float* inj_B  = (const float*)d_in[13];
    const float* act_w  = (const float*)d_in[14];
    const float* act_b  = (const float*)d_in[15];
    const float* loop_table = (const float*)d_in[16];

    char* p;
    if (ws_size >= WS_NEED) {
        p = (char*)d_ws;
    } else {
        void* sym = nullptr;
        hipGetSymbolAddress(&sym, HIP_SYMBOL(g_ws));
        p = (char*)sym;
    }

    float* h      = (float*)p;            p += (size_t)MR * DD * 4;      // 64 MiB
    unsigned short* he_bf = (unsigned short*)p; p += (size_t)MR * 2048 * 2; // 64
    unsigned short* xn_bf = (unsigned short*)p; p += (size_t)MR * DD * 2;   // 32
    unsigned short* q_bf  = (unsigned short*)p; p += (size_t)MR * DKK * 2;  // 32
    unsigned short* k_bf  = (unsigned short*)p; p += (size_t)MR * DKK * 2;  // 32
    unsigned short* v_bf  = (unsigned short*)p; p += (size_t)MR * DVV * 2;  // 64
    unsigned short* xg_bf = (unsigned short*)p; p += (size_t)MR * DVV * 2;  // 64
    float* lgbuf  = (float*)p;            p += (size_t)MR * DKK * 4;        // 64
    unsigned short* ob0   = (unsigned short*)p; p += (size_t)MR * DVV * 2;  // 64
    float* U      = (float*)p;            p += (size_t)NCH * 32 * DKH * DVH * 4; // 128
    float* dLe    = (float*)p;            p += (size_t)NCH * 32 * DKH * 4;
    unsigned short* WprojT = (unsigned short*)p; p += (size_t)NPROJ * DKK * 2;   // 14.7
    unsigned short* WoT    = (unsigned short*)p; p += (size_t)DD * DVV * 2;
    unsigned short* WinjT  = (unsigned short*)p; p += (size_t)DD * 2048 * 2;
    float* diagA = (float*)p;             p += DD * 4;
    float* tmp16 = (float*)p;             p += (size_t)MR * 16 * 4;
    float* cum   = (float*)p;             p += MR * 4;
    int*   halted = (int*)p;              p += MR * 4;
    // Aliases (lifetime-checked):
    float* g2 = lgbuf;              // lg consumed by c1; g2 written by Wo GEMM later
    float* h_out = (float*)d_out;

    hipMemcpyAsync(h, in_h, (size_t)MR * DD * 4, hipMemcpyDeviceToDevice, stream);
    hipMemsetAsync(h_out, 0, (size_t)MR * DD * 4, stream);
    hipMemsetAsync(cum, 0, MR * 4, stream);
    hipMemsetAsync(halted, 0, MR * 4, stream);

    // Weight prep
    k_transpose_bf16<<<dim3(16, 16), 256, 0, stream>>>(Wq,  WprojT,              DD, DKK);
    k_transpose_bf16<<<dim3(16, 16), 256, 0, stream>>>(Wk,  WprojT + 1024*1024,  DD, DKK);
    k_transpose_bf16<<<dim3(16, 16), 256, 0, stream>>>(Wgk, WprojT + 2048*1024,  DD, DKK);
    k_transpose_bf16<<<dim3(32, 16), 256, 0, stream>>>(Wv,  WprojT + 3072*1024,  DD, DVV);
    k_transpose_bf16<<<dim3(32, 16), 256, 0, stream>>>(Wg,  WprojT + (size_t)5120*1024, DD, DVV);
    k_transpose_bf16<<<dim3(16, 32), 256, 0, stream>>>(Wo,  WoT, DVV, DD);
    k_conv_injcomb<<<4096, 256, 0, stream>>>(inj_A, inj_B, WinjT, diagA);
    k_conv_e<<<MR * DD / 1024, 256, 0, stream>>>(in_e, he_bf);

    const float qscale = 0.08838834764831845f;   // 128^-0.5

    for (int t = 0; t < NLOOPS; ++t) {
        k_prep<<<MR, 256, 0, stream>>>(h, in_e, norm_w, loop_table + t * 128, he_bf, xn_bf);

        // fused 5-way projection
        k_gemm_proj<<<dim3(NPROJ/128, MR/128), 256, 0, stream>>>(
            xn_bf, WprojT, q_bf, k_bf, lgbuf, v_bf, xg_bf, qscale);

        // chunked GLA scan
        k_c1<<<dim3(NCH, 32), 128, 0, stream>>>(lgbuf, q_bf, k_bf, dLe);
        k_c2<<<dim3(NCH, 32), 256, 4 * LCH * PADW * 2, stream>>>(
            q_bf, k_bf, v_bf, ob0, U);
        k_c3<<<1024, 256, 0, stream>>>(U, dLe);
        k_c4<<<dim3(NCH, 32), 256, 2 * LCH * PADW * 2, stream>>>(q_bf, U, ob0, xg_bf);

        // Wo projection
        k_gemm_f32<0,0><<<dim3(DD/128, MR/128), 256, 0, stream>>>(
            ob0, WoT, g2, nullptr, nullptr, nullptr, DD, DVV);

        k_lora1<<<MR / 4, 256, 0, stream>>>(g2, lora_A + (size_t)t * DD * 16, tmp16);
        k_lora2<<<MR, 256, 0, stream>>>(g2, tmp16, lora_B + (size_t)t * 16 * DD);

        // h = [h|e] @ [injA|injB]^T + diagA*h + g2   (in place on h)
        k_gemm_f32<1,1><<<dim3(DD/128, MR/128), 256, 0, stream>>>(
            he_bf, WinjT, h, g2, h, diagA, DD, 2048);

        k_act<<<MR, 256, 0, stream>>>(h, act_w, act_b, h_out, cum, halted);
    }

    k_final<<<MR, 256, 0, stream>>>(h_out, out_norm_w);
}